// Round 1
// baseline (625.919 us; speedup 1.0000x reference)
//
#include <hip/hip_runtime.h>
#include <hip/hip_bf16.h>

#define NH 32
#define NKVH 8
#define DMODEL 2048
#define HDIM 64
#define NB 2
#define SEQ 2048
#define MROWS (NB*SEQ)      // 4096
#define NQ 2048
#define NKV 512
#define NTOT 3072

typedef __bf16 bf16x8 __attribute__((ext_vector_type(8)));
typedef float  f32x4  __attribute__((ext_vector_type(4)));

__device__ inline __bf16 f2bf(float f) {
    unsigned u = __builtin_bit_cast(unsigned, f);
    u += 0x7fff + ((u >> 16) & 1);               // RNE
    unsigned short s = (unsigned short)(u >> 16);
    return __builtin_bit_cast(__bf16, s);
}

// ---------------------------------------------------------------------------
// Kernel 0: fuse Wq|Wk|Wv (fp32, [K][N]) -> Wt bf16 [3072][2048] (N-major)
// ---------------------------------------------------------------------------
__global__ __launch_bounds__(256)
void transpose_w(const float* __restrict__ Wq,
                 const float* __restrict__ Wk,
                 const float* __restrict__ Wv,
                 __bf16* __restrict__ Wt)
{
    __shared__ __bf16 tile[64][72];
    int k0 = blockIdx.x * 64;     // 32 tiles
    int n0 = blockIdx.y * 64;     // 48 tiles
    const float* Wsrc; int ncols; int nbase;
    if (n0 < NQ)            { Wsrc = Wq; ncols = NQ;  nbase = n0; }
    else if (n0 < NQ + NKV) { Wsrc = Wk; ncols = NKV; nbase = n0 - NQ; }
    else                    { Wsrc = Wv; ncols = NKV; nbase = n0 - NQ - NKV; }
    int t = threadIdx.x;
    int kl = t >> 2;
    int nc = (t & 3) * 16;
    const float* src = Wsrc + (size_t)(k0 + kl) * ncols + nbase + nc;
    #pragma unroll
    for (int i = 0; i < 4; ++i) {
        f32x4 v = *reinterpret_cast<const f32x4*>(src + i * 4);
        #pragma unroll
        for (int e = 0; e < 4; ++e) tile[kl][nc + i * 4 + e] = f2bf(v[e]);
    }
    __syncthreads();
    int nl = t >> 2;
    int kc = (t & 3) * 16;
    bf16x8 o0, o1;
    #pragma unroll
    for (int i = 0; i < 8; ++i) o0[i] = tile[kc + i][nl];
    #pragma unroll
    for (int i = 0; i < 8; ++i) o1[i] = tile[kc + 8 + i][nl];
    __bf16* dst = Wt + (size_t)(n0 + nl) * DMODEL + k0 + kc;
    *reinterpret_cast<bf16x8*>(dst)     = o0;
    *reinterpret_cast<bf16x8*>(dst + 8) = o1;
}

// ---------------------------------------------------------------------------
// Kernel 1: QKV projection GEMM.  A = hidden fp32 [4096][2048],
// B = Wt bf16 [3072][2048] (row n, contiguous k).  C tiled 128x128, BK=64.
// Outputs: Q [B,NH,S,64], K [B,NKVH,S,64], Vt [B,NKVH,64,S]  (all bf16, +bias)
// ---------------------------------------------------------------------------
#define BM 128
#define BN 128
#define BK 64

__global__ __launch_bounds__(256)
void qkv_gemm(const float* __restrict__ Hs,
              const __bf16* __restrict__ Wt,
              const float* __restrict__ bq,
              const float* __restrict__ bk,
              const float* __restrict__ bv,
              __bf16* __restrict__ Qb,
              __bf16* __restrict__ Kb,
              __bf16* __restrict__ Vt)
{
    __shared__ __bf16 lds_a[BM * BK];
    __shared__ __bf16 lds_b[BN * BK];

    int n0 = blockIdx.x * BN;     // 24 tiles
    int m0 = blockIdx.y * BM;     // 32 tiles
    int t = threadIdx.x;
    int wave = t >> 6, lane = t & 63;
    int g = lane >> 4, lh = lane & 15;
    int wr = wave >> 1, wc = wave & 1;

    f32x4 acc[4][4] = {};

    int arow = t >> 1;            // 0..127
    int acol = (t & 1) * 32;      // elems

    for (int k0 = 0; k0 < DMODEL; k0 += BK) {
        // --- stage A (fp32 -> bf16, swizzled) ---
        const float* asrc = Hs + (size_t)(m0 + arow) * DMODEL + k0 + acol;
        float av[32];
        #pragma unroll
        for (int i = 0; i < 8; ++i) {
            f32x4 v = *reinterpret_cast<const f32x4*>(asrc + i * 4);
            av[i * 4 + 0] = v[0]; av[i * 4 + 1] = v[1];
            av[i * 4 + 2] = v[2]; av[i * 4 + 3] = v[3];
        }
        #pragma unroll
        for (int i = 0; i < 4; ++i) {
            bf16x8 w;
            #pragma unroll
            for (int e = 0; e < 8; ++e) w[e] = f2bf(av[i * 8 + e]);
            unsigned byte = (unsigned)(arow * (BK * 2) + (acol + i * 8) * 2) ^ ((arow & 7) << 4);
            *reinterpret_cast<bf16x8*>((char*)lds_a + byte) = w;
        }
        // --- stage B (bf16 copy, swizzled) ---
        const __bf16* bsrc = Wt + (size_t)(n0 + arow) * DMODEL + k0 + acol;
        #pragma unroll
        for (int i = 0; i < 4; ++i) {
            bf16x8 v = *reinterpret_cast<const bf16x8*>(bsrc + i * 8);
            unsigned byte = (unsigned)(arow * (BK * 2) + (acol + i * 8) * 2) ^ ((arow & 7) << 4);
            *reinterpret_cast<bf16x8*>((char*)lds_b + byte) = v;
        }
        __syncthreads();
        // --- MFMA ---
        #pragma unroll
        for (int kk = 0; kk < 2; ++kk) {
            bf16x8 af[4], bfr[4];
            #pragma unroll
            for (int mi = 0; mi < 4; ++mi) {
                int row = wr * 64 + mi * 16 + lh;
                unsigned byte = (unsigned)(row * (BK * 2) + (kk * 32 + g * 8) * 2) ^ ((row & 7) << 4);
                af[mi] = *reinterpret_cast<const bf16x8*>((const char*)lds_a + byte);
            }
            #pragma unroll
            for (int ni = 0; ni < 4; ++ni) {
                int col = wc * 64 + ni * 16 + lh;
                unsigned byte = (unsigned)(col * (BK * 2) + (kk * 32 + g * 8) * 2) ^ ((col & 7) << 4);
                bfr[ni] = *reinterpret_cast<const bf16x8*>((const char*)lds_b + byte);
            }
            #pragma unroll
            for (int mi = 0; mi < 4; ++mi)
                #pragma unroll
                for (int ni = 0; ni < 4; ++ni)
                    acc[mi][ni] = __builtin_amdgcn_mfma_f32_16x16x32_bf16(af[mi], bfr[ni], acc[mi][ni], 0, 0, 0);
        }
        __syncthreads();
    }

    // --- epilogue: bias + route to Q / K / Vt ---
    int mode = (n0 < NQ) ? 0 : (n0 < NQ + NKV ? 1 : 2);
    const float* bias = (mode == 0) ? bq : (mode == 1 ? bk : bv);
    int nsub = (mode == 0) ? 0 : (mode == 1 ? NQ : NQ + NKV);

    float biasv[4];
    #pragma unroll
    for (int ni = 0; ni < 4; ++ni)
        biasv[ni] = bias[n0 - nsub + wc * 64 + ni * 16 + lh];

    #pragma unroll
    for (int mi = 0; mi < 4; ++mi) {
        #pragma unroll
        for (int j = 0; j < 4; ++j) {
            int m = m0 + wr * 64 + mi * 16 + 4 * g + j;
            int bb = m >> 11, s = m & (SEQ - 1);
            #pragma unroll
            for (int ni = 0; ni < 4; ++ni) {
                int n = n0 + wc * 64 + ni * 16 + lh;
                __bf16 val = f2bf(acc[mi][ni][j] + biasv[ni]);
                if (mode == 0) {
                    int hh = n >> 6, d = n & 63;
                    Qb[(((size_t)bb * NH + hh) * SEQ + s) * HDIM + d] = val;
                } else if (mode == 1) {
                    int nk = n - NQ; int kv = nk >> 6, d = nk & 63;
                    Kb[(((size_t)bb * NKVH + kv) * SEQ + s) * HDIM + d] = val;
                } else {
                    int nv = n - NQ - NKV; int kv = nv >> 6, d = nv & 63;
                    Vt[(((size_t)bb * NKVH + kv) * HDIM + d) * SEQ + s] = val;
                }
            }
        }
    }
}

// ---------------------------------------------------------------------------
// Kernel 2: flash attention.  Block = 64 q-rows of one (b,h); 4 waves x 16 rows.
// KV tile = 64 keys.  K/V fragments straight from global (L2-resident).
// ---------------------------------------------------------------------------
__global__ __launch_bounds__(256)
void attn(const __bf16* __restrict__ Qb,
          const __bf16* __restrict__ Kb,
          const __bf16* __restrict__ Vt,
          float* __restrict__ out)
{
    __shared__ __bf16 lds_p[4 * 16 * 64];   // per-wave 16x64 P, XOR-swizzled

    int qt = blockIdx.x;          // 0..31
    int bh = blockIdx.y;          // 0..63
    int b = bh >> 5, h = bh & 31;
    int kvh = h >> 2;             // REP = 4
    int t = threadIdx.x, wave = t >> 6, lane = t & 63;
    int g = lane >> 4, lh = lane & 15;
    int q0 = qt * 64 + wave * 16;

    const __bf16* Qp = Qb + ((size_t)(b * NH + h) * SEQ) * HDIM;
    const __bf16* Kp = Kb + ((size_t)(b * NKVH + kvh) * SEQ) * HDIM;
    const __bf16* Vp = Vt + ((size_t)(b * NKVH + kvh) * HDIM) * SEQ;
    __bf16* pb = lds_p + wave * 16 * 64;

    bf16x8 aq[2];
    #pragma unroll
    for (int f = 0; f < 2; ++f)
        aq[f] = *reinterpret_cast<const bf16x8*>(Qp + (size_t)(q0 + lh) * HDIM + f * 32 + g * 8);

    f32x4 acc[4] = {};            // [ni over d]; rows 4g+j
    float m_run[4], l_run[4];
    #pragma unroll
    for (int j = 0; j < 4; ++j) { m_run[j] = -1e30f; l_run[j] = 0.0f; }

    const float SC = 0.18033688011112042f;   // (1/8) * log2(e)

    for (int kt = 0; kt < SEQ / 64; ++kt) {
        int kbase = kt * 64;
        // ---- QK^T ----
        f32x4 sc[4];
        #pragma unroll
        for (int c = 0; c < 4; ++c) {
            const __bf16* kp = Kp + (size_t)(kbase + c * 16 + lh) * HDIM + g * 8;
            bf16x8 kf0 = *reinterpret_cast<const bf16x8*>(kp);
            bf16x8 kf1 = *reinterpret_cast<const bf16x8*>(kp + 32);
            f32x4 z = {};
            z = __builtin_amdgcn_mfma_f32_16x16x32_bf16(aq[0], kf0, z, 0, 0, 0);
            z = __builtin_amdgcn_mfma_f32_16x16x32_bf16(aq[1], kf1, z, 0, 0, 0);
            sc[c] = z;
        }
        // ---- online softmax ----
        float p[4][4];
        #pragma unroll
        for (int j = 0; j < 4; ++j) {
            float mt = fmaxf(fmaxf(sc[0][j], sc[1][j]), fmaxf(sc[2][j], sc[3][j]));
            mt = fmaxf(mt, __shfl_xor(mt, 1));
            mt = fmaxf(mt, __shfl_xor(mt, 2));
            mt = fmaxf(mt, __shfl_xor(mt, 4));
            mt = fmaxf(mt, __shfl_xor(mt, 8));
            float mn = fmaxf(m_run[j], mt);
            float alpha = __builtin_amdgcn_exp2f((m_run[j] - mn) * SC);
            m_run[j] = mn;
            float ps = 0.0f;
            #pragma unroll
            for (int c = 0; c < 4; ++c) {
                float pv = __builtin_amdgcn_exp2f((sc[c][j] - mn) * SC);
                p[c][j] = pv;
                ps += pv;
            }
            ps += __shfl_xor(ps, 1);
            ps += __shfl_xor(ps, 2);
            ps += __shfl_xor(ps, 4);
            ps += __shfl_xor(ps, 8);
            l_run[j] = l_run[j] * alpha + ps;
            #pragma unroll
            for (int ni = 0; ni < 4; ++ni) acc[ni][j] *= alpha;
        }
        // ---- P -> LDS (bf16, swizzled), C-layout write ----
        #pragma unroll
        for (int c = 0; c < 4; ++c) {
            #pragma unroll
            for (int j = 0; j < 4; ++j) {
                int q = 4 * g + j;
                unsigned byte = (unsigned)(q * 128 + (c * 16 + lh) * 2) ^ ((q & 7) << 4);
                *reinterpret_cast<__bf16*>((char*)pb + byte) = f2bf(p[c][j]);
            }
        }
        // ---- PV ----  (same-wave LDS: compiler inserts lgkmcnt waits)
        #pragma unroll
        for (int kk = 0; kk < 2; ++kk) {
            unsigned byte = (unsigned)(lh * 128 + (kk * 32 + g * 8) * 2) ^ ((lh & 7) << 4);
            bf16x8 pa = *reinterpret_cast<const bf16x8*>((const char*)pb + byte);
            #pragma unroll
            for (int ni = 0; ni < 4; ++ni) {
                const __bf16* vp = Vp + (size_t)(ni * 16 + lh) * SEQ + kbase + kk * 32 + g * 8;
                bf16x8 vb = *reinterpret_cast<const bf16x8*>(vp);
                acc[ni] = __builtin_amdgcn_mfma_f32_16x16x32_bf16(pa, vb, acc[ni], 0, 0, 0);
            }
        }
    }
    // ---- epilogue ----
    #pragma unroll
    for (int j = 0; j < 4; ++j) {
        float inv = 1.0f / l_run[j];
        int row = q0 + 4 * g + j;
        float* op = out + ((size_t)b * SEQ + row) * DMODEL + h * HDIM;
        #pragma unroll
        for (int ni = 0; ni < 4; ++ni)
            op[ni * 16 + lh] = acc[ni][j] * inv;
    }
}

// ---------------------------------------------------------------------------
extern "C" void kernel_launch(void* const* d_in, const int* in_sizes, int n_in,
                              void* d_out, int out_size, void* d_ws, size_t ws_size,
                              hipStream_t stream)
{
    const float* hs = (const float*)d_in[0];
    const float* Wq = (const float*)d_in[1];
    const float* bq = (const float*)d_in[2];
    const float* Wk = (const float*)d_in[3];
    const float* bk = (const float*)d_in[4];
    const float* Wv = (const float*)d_in[5];
    const float* bv = (const float*)d_in[6];
    float* out = (float*)d_out;

    char* ws = (char*)d_ws;
    __bf16* Wt = (__bf16*)(ws);                                   // 12,582,912 B
    __bf16* Qb = (__bf16*)(ws + 12582912);                        // 16,777,216 B
    __bf16* Kb = (__bf16*)(ws + 12582912 + 16777216);             //  4,194,304 B
    __bf16* Vt = (__bf16*)(ws + 12582912 + 16777216 + 4194304);   //  4,194,304 B

    hipLaunchKernelGGL(transpose_w, dim3(32, 48), dim3(256), 0, stream, Wq, Wk, Wv, Wt);
    hipLaunchKernelGGL(qkv_gemm,    dim3(24, 32), dim3(256), 0, stream, hs, Wt, bq, bk, bv, Qb, Kb, Vt);
    hipLaunchKernelGGL(attn,        dim3(32, 64), dim3(256), 0, stream, Qb, Kb, Vt, out);
}

// Round 4
// 515.518 us; speedup vs baseline: 1.2142x; 1.2142x over previous
//
#include <hip/hip_runtime.h>
#include <hip/hip_bf16.h>

#define NH 32
#define NKVH 8
#define DMODEL 2048
#define HDIM 64
#define NB 2
#define SEQ 2048
#define MROWS (NB*SEQ)      // 4096
#define NQ 2048
#define NKV 512
#define NTOT 3072

typedef __bf16 bf16x4 __attribute__((ext_vector_type(4)));
typedef __bf16 bf16x8 __attribute__((ext_vector_type(8)));
typedef float  f32x4  __attribute__((ext_vector_type(4)));
typedef float  f32x16 __attribute__((ext_vector_type(16)));
typedef unsigned u32x4 __attribute__((ext_vector_type(4)));

__device__ inline __bf16 f2bf(float f) {
    unsigned u = __builtin_bit_cast(unsigned, f);
    u += 0x7fff + ((u >> 16) & 1);               // RNE
    unsigned short s = (unsigned short)(u >> 16);
    return __builtin_bit_cast(__bf16, s);
}

// pack two f32 -> one u32 holding 2x bf16 (lo = a, hi = b); plain bit-ops
__device__ inline unsigned pack2bf(float a, float b) {
    unsigned ua = __builtin_bit_cast(unsigned, a);
    ua += 0x7fff + ((ua >> 16) & 1);
    unsigned ub = __builtin_bit_cast(unsigned, b);
    ub += 0x7fff + ((ub >> 16) & 1);
    return (ua >> 16) | (ub & 0xffff0000u);
}

// cross-half (lane ^ 32) combine via plain shuffles (R1-proven path)
__device__ inline float cross_max32(float x) {
    return fmaxf(x, __shfl_xor(x, 32));
}
__device__ inline float cross_add32(float x) {
    return x + __shfl_xor(x, 32);
}

// ---------------------------------------------------------------------------
// Kernel 0: fuse Wq|Wk|Wv (fp32, [K][N]) -> Wt bf16 [3072][2048] (N-major)
// ---------------------------------------------------------------------------
__global__ __launch_bounds__(256)
void transpose_w(const float* __restrict__ Wq,
                 const float* __restrict__ Wk,
                 const float* __restrict__ Wv,
                 __bf16* __restrict__ Wt)
{
    __shared__ __bf16 tile[64][72];
    int k0 = blockIdx.x * 64;     // 32 tiles
    int n0 = blockIdx.y * 64;     // 48 tiles
    const float* Wsrc; int ncols; int nbase;
    if (n0 < NQ)            { Wsrc = Wq; ncols = NQ;  nbase = n0; }
    else if (n0 < NQ + NKV) { Wsrc = Wk; ncols = NKV; nbase = n0 - NQ; }
    else                    { Wsrc = Wv; ncols = NKV; nbase = n0 - NQ - NKV; }
    int t = threadIdx.x;
    int kl = t >> 2;
    int nc = (t & 3) * 16;
    const float* src = Wsrc + (size_t)(k0 + kl) * ncols + nbase + nc;
    #pragma unroll
    for (int i = 0; i < 4; ++i) {
        f32x4 v = *reinterpret_cast<const f32x4*>(src + i * 4);
        #pragma unroll
        for (int e = 0; e < 4; ++e) tile[kl][nc + i * 4 + e] = f2bf(v[e]);
    }
    __syncthreads();
    int nl = t >> 2;
    int kc = (t & 3) * 16;
    bf16x8 o0, o1;
    #pragma unroll
    for (int i = 0; i < 8; ++i) o0[i] = tile[kc + i][nl];
    #pragma unroll
    for (int i = 0; i < 8; ++i) o1[i] = tile[kc + 8 + i][nl];
    __bf16* dst = Wt + (size_t)(n0 + nl) * DMODEL + k0 + kc;
    *reinterpret_cast<bf16x8*>(dst)     = o0;
    *reinterpret_cast<bf16x8*>(dst + 8) = o1;
}

// ---------------------------------------------------------------------------
// Kernel 1: QKV projection GEMM.  A = hidden fp32 [4096][2048],
// B = Wt bf16 [3072][2048] (row n, contiguous k).  C tiled 128x128, BK=64.
// Outputs: Q [B,NH,S,64], K [B,NKVH,S,64], Vt [B,NKVH,64,S]  (all bf16, +bias)
// ---------------------------------------------------------------------------
#define BM 128
#define BN 128
#define BK 64

__global__ __launch_bounds__(256)
void qkv_gemm(const float* __restrict__ Hs,
              const __bf16* __restrict__ Wt,
              const float* __restrict__ bq,
              const float* __restrict__ bk,
              const float* __restrict__ bv,
              __bf16* __restrict__ Qb,
              __bf16* __restrict__ Kb,
              __bf16* __restrict__ Vt)
{
    __shared__ __bf16 lds_a[BM * BK];
    __shared__ __bf16 lds_b[BN * BK];

    int n0 = blockIdx.x * BN;     // 24 tiles
    int m0 = blockIdx.y * BM;     // 32 tiles
    int t = threadIdx.x;
    int wave = t >> 6, lane = t & 63;
    int g = lane >> 4, lh = lane & 15;
    int wr = wave >> 1, wc = wave & 1;

    f32x4 acc[4][4] = {};

    int arow = t >> 1;            // 0..127
    int acol = (t & 1) * 32;      // elems

    for (int k0 = 0; k0 < DMODEL; k0 += BK) {
        // --- stage A (fp32 -> bf16, swizzled) ---
        const float* asrc = Hs + (size_t)(m0 + arow) * DMODEL + k0 + acol;
        float av[32];
        #pragma unroll
        for (int i = 0; i < 8; ++i) {
            f32x4 v = *reinterpret_cast<const f32x4*>(asrc + i * 4);
            av[i * 4 + 0] = v[0]; av[i * 4 + 1] = v[1];
            av[i * 4 + 2] = v[2]; av[i * 4 + 3] = v[3];
        }
        #pragma unroll
        for (int i = 0; i < 4; ++i) {
            bf16x8 w;
            #pragma unroll
            for (int e = 0; e < 8; ++e) w[e] = f2bf(av[i * 8 + e]);
            unsigned byte = (unsigned)(arow * (BK * 2) + (acol + i * 8) * 2) ^ ((arow & 7) << 4);
            *reinterpret_cast<bf16x8*>((char*)lds_a + byte) = w;
        }
        // --- stage B (bf16 copy, swizzled) ---
        const __bf16* bsrc = Wt + (size_t)(n0 + arow) * DMODEL + k0 + acol;
        #pragma unroll
        for (int i = 0; i < 4; ++i) {
            bf16x8 v = *reinterpret_cast<const bf16x8*>(bsrc + i * 8);
            unsigned byte = (unsigned)(arow * (BK * 2) + (acol + i * 8) * 2) ^ ((arow & 7) << 4);
            *reinterpret_cast<bf16x8*>((char*)lds_b + byte) = v;
        }
        __syncthreads();
        // --- MFMA ---
        #pragma unroll
        for (int kk = 0; kk < 2; ++kk) {
            bf16x8 af[4], bfr[4];
            #pragma unroll
            for (int mi = 0; mi < 4; ++mi) {
                int row = wr * 64 + mi * 16 + lh;
                unsigned byte = (unsigned)(row * (BK * 2) + (kk * 32 + g * 8) * 2) ^ ((row & 7) << 4);
                af[mi] = *reinterpret_cast<const bf16x8*>((const char*)lds_a + byte);
            }
            #pragma unroll
            for (int ni = 0; ni < 4; ++ni) {
                int col = wc * 64 + ni * 16 + lh;
                unsigned byte = (unsigned)(col * (BK * 2) + (kk * 32 + g * 8) * 2) ^ ((col & 7) << 4);
                bfr[ni] = *reinterpret_cast<const bf16x8*>((const char*)lds_b + byte);
            }
            #pragma unroll
            for (int mi = 0; mi < 4; ++mi)
                #pragma unroll
                for (int ni = 0; ni < 4; ++ni)
                    acc[mi][ni] = __builtin_amdgcn_mfma_f32_16x16x32_bf16(af[mi], bfr[ni], acc[mi][ni], 0, 0, 0);
        }
        __syncthreads();
    }

    // --- epilogue: bias + route to Q / K / Vt ---
    int mode = (n0 < NQ) ? 0 : (n0 < NQ + NKV ? 1 : 2);
    const float* bias = (mode == 0) ? bq : (mode == 1 ? bk : bv);
    int nsub = (mode == 0) ? 0 : (mode == 1 ? NQ : NQ + NKV);

    float biasv[4];
    #pragma unroll
    for (int ni = 0; ni < 4; ++ni)
        biasv[ni] = bias[n0 - nsub + wc * 64 + ni * 16 + lh];

    #pragma unroll
    for (int mi = 0; mi < 4; ++mi) {
        #pragma unroll
        for (int j = 0; j < 4; ++j) {
            int m = m0 + wr * 64 + mi * 16 + 4 * g + j;
            int bb = m >> 11, s = m & (SEQ - 1);
            #pragma unroll
            for (int ni = 0; ni < 4; ++ni) {
                int n = n0 + wc * 64 + ni * 16 + lh;
                __bf16 val = f2bf(acc[mi][ni][j] + biasv[ni]);
                if (mode == 0) {
                    int hh = n >> 6, d = n & 63;
                    Qb[(((size_t)bb * NH + hh) * SEQ + s) * HDIM + d] = val;
                } else if (mode == 1) {
                    int nk = n - NQ; int kv = nk >> 6, d = nk & 63;
                    Kb[(((size_t)bb * NKVH + kv) * SEQ + s) * HDIM + d] = val;
                } else {
                    int nv = n - NQ - NKV; int kv = nv >> 6, d = nv & 63;
                    Vt[(((size_t)bb * NKVH + kv) * HDIM + d) * SEQ + s] = val;
                }
            }
        }
    }
}

// ---------------------------------------------------------------------------
// Kernel 2: flash attention, swapped-operand 32x32 structure.
// Block = 128 q-rows of one (b,h); 4 waves x 32 q-rows. KV tile = 64 keys.
// S^T = mfma(K, Q^T)  -> lane holds P-row slice for q = lane&31 (in-register
// softmax; cross-half merge via __shfl_xor(32)).
// PV uses a k-PERMUTED contraction: P fragment for slot ks is p[8ks..8ks+7]
// in natural register order (no cross-lane movement); V rows are loaded at
// the matching permuted keys kappa = 16ks + 8(e>>2) + 4hi + (e&3).
// O^T = mfma(V~, P~) -> acc column is q = lane&31, so rescale is lane-local.
// ---------------------------------------------------------------------------
__global__ __launch_bounds__(256)
void attn(const __bf16* __restrict__ Qb,
          const __bf16* __restrict__ Kb,
          const __bf16* __restrict__ Vt,
          float* __restrict__ out)
{
    int qt = blockIdx.x;          // 0..15
    int bh = blockIdx.y;          // 0..63
    int b = bh >> 5, h = bh & 31;
    int kvh = h >> 2;             // REP = 4
    int lane = threadIdx.x & 63, wave = (int)threadIdx.x >> 6;
    int ql = lane & 31, hi = lane >> 5;
    int q0 = qt * 128 + wave * 32;

    const __bf16* Qp = Qb + (size_t)(b * NH + h) * SEQ * HDIM;
    const __bf16* Kp = Kb + (size_t)(b * NKVH + kvh) * SEQ * HDIM;
    const __bf16* Vp = Vt + (size_t)(b * NKVH + kvh) * HDIM * SEQ;

    // Q^T B-operand fragments: B[d][q], lane -> col q=ql, rows d = f*16+hi*8+e
    bf16x8 qf[4];
    #pragma unroll
    for (int f = 0; f < 4; ++f)
        qf[f] = *reinterpret_cast<const bf16x8*>(Qp + (size_t)(q0 + ql) * HDIM + f * 16 + hi * 8);

    f32x16 accO0 = {}, accO1 = {};   // O^T[d][q]: d-blocks 0..31 / 32..63
    float m_run = -1e30f, l_run = 0.0f;
    const float SC = 0.18033688011112042f;   // (1/8) * log2(e)

    for (int kt = 0; kt < SEQ / 64; ++kt) {
        int kbase = kt * 64;
        // ---- K A-operand fragments: A[k][d], row k = kb*32+ql ----
        bf16x8 kf[8];
        #pragma unroll
        for (int kb = 0; kb < 2; ++kb)
            #pragma unroll
            for (int f = 0; f < 4; ++f)
                kf[kb * 4 + f] = *reinterpret_cast<const bf16x8*>(
                    Kp + (size_t)(kbase + kb * 32 + ql) * HDIM + f * 16 + hi * 8);
        // ---- S^T = K . Q^T  (two 32x32 k-blocks) ----
        f32x16 s0 = {}, s1 = {};
        #pragma unroll
        for (int f = 0; f < 4; ++f) {
            s0 = __builtin_amdgcn_mfma_f32_32x32x16_bf16(kf[f],     qf[f], s0, 0, 0, 0);
            s1 = __builtin_amdgcn_mfma_f32_32x32x16_bf16(kf[4 + f], qf[f], s1, 0, 0, 0);
        }
        // lane (q=ql, hi) holds S[q][k]: k_local = kb*32 + (r&3) + 8*(r>>2) + 4*hi
        // => p[4m+j] holds k_local = 8m + 4hi + j   (m=0..7, j=0..3)
        // ---- in-register online softmax ----
        float tm[16];
        #pragma unroll
        for (int r = 0; r < 16; ++r) tm[r] = fmaxf(s0[r], s1[r]);
        #pragma unroll
        for (int st = 8; st > 0; st >>= 1)
            #pragma unroll
            for (int r = 0; r < st; ++r) tm[r] = fmaxf(tm[r], tm[r + st]);
        float mt = cross_max32(tm[0]);
        float mn = fmaxf(m_run, mt);
        float alpha = __builtin_amdgcn_exp2f((m_run - mn) * SC);
        m_run = mn;
        float p[32];
        #pragma unroll
        for (int r = 0; r < 16; ++r) {
            p[r]      = __builtin_amdgcn_exp2f((s0[r] - mn) * SC);
            p[16 + r] = __builtin_amdgcn_exp2f((s1[r] - mn) * SC);
        }
        float ts[16];
        #pragma unroll
        for (int r = 0; r < 16; ++r) ts[r] = p[r] + p[16 + r];
        #pragma unroll
        for (int st = 8; st > 0; st >>= 1)
            #pragma unroll
            for (int r = 0; r < st; ++r) ts[r] += ts[r + st];
        float ps = cross_add32(ts[0]);
        l_run = l_run * alpha + ps;
        accO0 *= alpha;
        accO1 *= alpha;
        // ---- P fragments: slot ks, element e = p[8ks+e]  (k-permuted) ----
        bf16x8 pfr[4];
        #pragma unroll
        for (int ks = 0; ks < 4; ++ks) {
            u32x4 wv;
            #pragma unroll
            for (int tt = 0; tt < 4; ++tt)
                wv[tt] = pack2bf(p[ks * 8 + 2 * tt], p[ks * 8 + 2 * tt + 1]);
            pfr[ks] = __builtin_bit_cast(bf16x8, wv);
        }
        // ---- O^T += V~ . P~  (V rows at permuted key kappa) ----
        #pragma unroll
        for (int ks = 0; ks < 4; ++ks) {
            const __bf16* vb0 = Vp + (size_t)ql * SEQ        + kbase + ks * 16 + hi * 4;
            const __bf16* vb1 = Vp + (size_t)(32 + ql) * SEQ + kbase + ks * 16 + hi * 4;
            bf16x4 a0 = *reinterpret_cast<const bf16x4*>(vb0);
            bf16x4 a1 = *reinterpret_cast<const bf16x4*>(vb0 + 8);
            bf16x4 b0 = *reinterpret_cast<const bf16x4*>(vb1);
            bf16x4 b1 = *reinterpret_cast<const bf16x4*>(vb1 + 8);
            bf16x8 v0 = __builtin_shufflevector(a0, a1, 0, 1, 2, 3, 4, 5, 6, 7);
            bf16x8 v1 = __builtin_shufflevector(b0, b1, 0, 1, 2, 3, 4, 5, 6, 7);
            accO0 = __builtin_amdgcn_mfma_f32_32x32x16_bf16(v0, pfr[ks], accO0, 0, 0, 0);
            accO1 = __builtin_amdgcn_mfma_f32_32x32x16_bf16(v1, pfr[ks], accO1, 0, 0, 0);
        }
    }
    // ---- epilogue: lane q = ql fixed; d = (r&3) + 8*(r>>2) + 4*hi (+32 for accO1)
    float inv = 1.0f / l_run;
    float* op = out + ((size_t)b * SEQ + q0 + ql) * DMODEL + h * HDIM;
    #pragma unroll
    for (int G = 0; G < 4; ++G) {
        f32x4 o0 = { accO0[4 * G + 0] * inv, accO0[4 * G + 1] * inv,
                     accO0[4 * G + 2] * inv, accO0[4 * G + 3] * inv };
        f32x4 o1 = { accO1[4 * G + 0] * inv, accO1[4 * G + 1] * inv,
                     accO1[4 * G + 2] * inv, accO1[4 * G + 3] * inv };
        *reinterpret_cast<f32x4*>(op + 8 * G + 4 * hi)      = o0;
        *reinterpret_cast<f32x4*>(op + 32 + 8 * G + 4 * hi) = o1;
    }
}

// ---------------------------------------------------------------------------
extern "C" void kernel_launch(void* const* d_in, const int* in_sizes, int n_in,
                              void* d_out, int out_size, void* d_ws, size_t ws_size,
                              hipStream_t stream)
{
    const float* hs = (const float*)d_in[0];
    const float* Wq = (const float*)d_in[1];
    const float* bq = (const float*)d_in[2];
    const float* Wk = (const float*)d_in[3];
    const float* bk = (const float*)d_in[4];
    const float* Wv = (const float*)d_in[5];
    const float* bv = (const float*)d_in[6];
    float* out = (float*)d_out;

    char* ws = (char*)d_ws;
    __bf16* Wt = (__bf16*)(ws);                                   // 12,582,912 B
    __bf16* Qb = (__bf16*)(ws + 12582912);                        // 16,777,216 B
    __bf16* Kb = (__bf16*)(ws + 12582912 + 16777216);             //  4,194,304 B
    __bf16* Vt = (__bf16*)(ws + 12582912 + 16777216 + 4194304);   //  4,194,304 B

    hipLaunchKernelGGL(transpose_w, dim3(32, 48), dim3(256), 0, stream, Wq, Wk, Wv, Wt);
    hipLaunchKernelGGL(qkv_gemm,    dim3(24, 32), dim3(256), 0, stream, hs, Wt, bq, bk, bv, Qb, Kb, Vt);
    hipLaunchKernelGGL(attn,        dim3(16, 64), dim3(256), 0, stream, Qb, Kb, Vt, out);
}

// Round 5
// 269.815 us; speedup vs baseline: 2.3198x; 1.9106x over previous
//
#include <hip/hip_runtime.h>
#include <hip/hip_bf16.h>

#define NH 32
#define NKVH 8
#define DMODEL 2048
#define HDIM 64
#define NB 2
#define SEQ 2048
#define MROWS (NB*SEQ)      // 4096
#define NQ 2048
#define NKV 512
#define NTOT 3072
#define NT (SEQ/64)         // 32 kv tiles

typedef __bf16 bf16x4 __attribute__((ext_vector_type(4)));
typedef __bf16 bf16x8 __attribute__((ext_vector_type(8)));
typedef float  f32x4  __attribute__((ext_vector_type(4)));
typedef float  f32x16 __attribute__((ext_vector_type(16)));
typedef unsigned u32x4 __attribute__((ext_vector_type(4)));

__device__ inline __bf16 f2bf(float f) {
    unsigned u = __builtin_bit_cast(unsigned, f);
    u += 0x7fff + ((u >> 16) & 1);               // RNE
    unsigned short s = (unsigned short)(u >> 16);
    return __builtin_bit_cast(__bf16, s);
}

// pack two f32 -> one u32 holding 2x bf16 (lo = a, hi = b); plain bit-ops
__device__ inline unsigned pack2bf(float a, float b) {
    unsigned ua = __builtin_bit_cast(unsigned, a);
    ua += 0x7fff + ((ua >> 16) & 1);
    unsigned ub = __builtin_bit_cast(unsigned, b);
    ub += 0x7fff + ((ub >> 16) & 1);
    return (ua >> 16) | (ub & 0xffff0000u);
}

__device__ inline void gload_lds16(const void* g, void* l) {
    __builtin_amdgcn_global_load_lds(
        (const __attribute__((address_space(1))) void*)g,
        (__attribute__((address_space(3))) void*)l, 16, 0, 0);
}

// ---------------------------------------------------------------------------
// Kernel 0: fuse Wq|Wk|Wv (fp32, [K][N]) -> Wt bf16 [3072][2048] (N-major)
// ---------------------------------------------------------------------------
__global__ __launch_bounds__(256)
void transpose_w(const float* __restrict__ Wq,
                 const float* __restrict__ Wk,
                 const float* __restrict__ Wv,
                 __bf16* __restrict__ Wt)
{
    __shared__ __bf16 tile[64][72];
    int k0 = blockIdx.x * 64;     // 32 tiles
    int n0 = blockIdx.y * 64;     // 48 tiles
    const float* Wsrc; int ncols; int nbase;
    if (n0 < NQ)            { Wsrc = Wq; ncols = NQ;  nbase = n0; }
    else if (n0 < NQ + NKV) { Wsrc = Wk; ncols = NKV; nbase = n0 - NQ; }
    else                    { Wsrc = Wv; ncols = NKV; nbase = n0 - NQ - NKV; }
    int t = threadIdx.x;
    int kl = t >> 2;
    int nc = (t & 3) * 16;
    const float* src = Wsrc + (size_t)(k0 + kl) * ncols + nbase + nc;
    #pragma unroll
    for (int i = 0; i < 4; ++i) {
        f32x4 v = *reinterpret_cast<const f32x4*>(src + i * 4);
        #pragma unroll
        for (int e = 0; e < 4; ++e) tile[kl][nc + i * 4 + e] = f2bf(v[e]);
    }
    __syncthreads();
    int nl = t >> 2;
    int kc = (t & 3) * 16;
    bf16x8 o0, o1;
    #pragma unroll
    for (int i = 0; i < 8; ++i) o0[i] = tile[kc + i][nl];
    #pragma unroll
    for (int i = 0; i < 8; ++i) o1[i] = tile[kc + 8 + i][nl];
    __bf16* dst = Wt + (size_t)(n0 + nl) * DMODEL + k0 + kc;
    *reinterpret_cast<bf16x8*>(dst)     = o0;
    *reinterpret_cast<bf16x8*>(dst + 8) = o1;
}

// ---------------------------------------------------------------------------
// Kernel 1: QKV projection GEMM.  A = hidden fp32 [4096][2048],
// B = Wt bf16 [3072][2048] (row n, contiguous k).  C tiled 128x128, BK=64.
// Outputs: Q [B,NH,S,64] PRE-SCALED by (1/8)*log2(e), K [B,NKVH,S,64],
//          Vt [B,NKVH,64,S]  (all bf16, +bias)
// ---------------------------------------------------------------------------
#define BM 128
#define BN 128
#define BK 64

__global__ __launch_bounds__(256)
void qkv_gemm(const float* __restrict__ Hs,
              const __bf16* __restrict__ Wt,
              const float* __restrict__ bq,
              const float* __restrict__ bk,
              const float* __restrict__ bv,
              __bf16* __restrict__ Qb,
              __bf16* __restrict__ Kb,
              __bf16* __restrict__ Vt)
{
    __shared__ __bf16 lds_a[BM * BK];
    __shared__ __bf16 lds_b[BN * BK];

    int n0 = blockIdx.x * BN;     // 24 tiles
    int m0 = blockIdx.y * BM;     // 32 tiles
    int t = threadIdx.x;
    int wave = t >> 6, lane = t & 63;
    int g = lane >> 4, lh = lane & 15;
    int wr = wave >> 1, wc = wave & 1;

    f32x4 acc[4][4] = {};

    int arow = t >> 1;            // 0..127
    int acol = (t & 1) * 32;      // elems

    for (int k0 = 0; k0 < DMODEL; k0 += BK) {
        // --- stage A (fp32 -> bf16, swizzled) ---
        const float* asrc = Hs + (size_t)(m0 + arow) * DMODEL + k0 + acol;
        float av[32];
        #pragma unroll
        for (int i = 0; i < 8; ++i) {
            f32x4 v = *reinterpret_cast<const f32x4*>(asrc + i * 4);
            av[i * 4 + 0] = v[0]; av[i * 4 + 1] = v[1];
            av[i * 4 + 2] = v[2]; av[i * 4 + 3] = v[3];
        }
        #pragma unroll
        for (int i = 0; i < 4; ++i) {
            bf16x8 w;
            #pragma unroll
            for (int e = 0; e < 8; ++e) w[e] = f2bf(av[i * 8 + e]);
            unsigned byte = (unsigned)(arow * (BK * 2) + (acol + i * 8) * 2) ^ ((arow & 7) << 4);
            *reinterpret_cast<bf16x8*>((char*)lds_a + byte) = w;
        }
        // --- stage B (bf16 copy, swizzled) ---
        const __bf16* bsrc = Wt + (size_t)(n0 + arow) * DMODEL + k0 + acol;
        #pragma unroll
        for (int i = 0; i < 4; ++i) {
            bf16x8 v = *reinterpret_cast<const bf16x8*>(bsrc + i * 8);
            unsigned byte = (unsigned)(arow * (BK * 2) + (acol + i * 8) * 2) ^ ((arow & 7) << 4);
            *reinterpret_cast<bf16x8*>((char*)lds_b + byte) = v;
        }
        __syncthreads();
        // --- MFMA ---
        #pragma unroll
        for (int kk = 0; kk < 2; ++kk) {
            bf16x8 af[4], bfr[4];
            #pragma unroll
            for (int mi = 0; mi < 4; ++mi) {
                int row = wr * 64 + mi * 16 + lh;
                unsigned byte = (unsigned)(row * (BK * 2) + (kk * 32 + g * 8) * 2) ^ ((row & 7) << 4);
                af[mi] = *reinterpret_cast<const bf16x8*>((const char*)lds_a + byte);
            }
            #pragma unroll
            for (int ni = 0; ni < 4; ++ni) {
                int col = wc * 64 + ni * 16 + lh;
                unsigned byte = (unsigned)(col * (BK * 2) + (kk * 32 + g * 8) * 2) ^ ((col & 7) << 4);
                bfr[ni] = *reinterpret_cast<const bf16x8*>((const char*)lds_b + byte);
            }
            #pragma unroll
            for (int mi = 0; mi < 4; ++mi)
                #pragma unroll
                for (int ni = 0; ni < 4; ++ni)
                    acc[mi][ni] = __builtin_amdgcn_mfma_f32_16x16x32_bf16(af[mi], bfr[ni], acc[mi][ni], 0, 0, 0);
        }
        __syncthreads();
    }

    // --- epilogue: bias + route to Q / K / Vt ---
    int mode = (n0 < NQ) ? 0 : (n0 < NQ + NKV ? 1 : 2);
    const float* bias = (mode == 0) ? bq : (mode == 1 ? bk : bv);
    int nsub = (mode == 0) ? 0 : (mode == 1 ? NQ : NQ + NKV);
    float scale = (mode == 0) ? 0.18033688011112042f : 1.0f;  // (1/8)*log2(e)

    float biasv[4];
    #pragma unroll
    for (int ni = 0; ni < 4; ++ni)
        biasv[ni] = bias[n0 - nsub + wc * 64 + ni * 16 + lh];

    #pragma unroll
    for (int mi = 0; mi < 4; ++mi) {
        #pragma unroll
        for (int j = 0; j < 4; ++j) {
            int m = m0 + wr * 64 + mi * 16 + 4 * g + j;
            int bb = m >> 11, s = m & (SEQ - 1);
            #pragma unroll
            for (int ni = 0; ni < 4; ++ni) {
                int n = n0 + wc * 64 + ni * 16 + lh;
                __bf16 val = f2bf((acc[mi][ni][j] + biasv[ni]) * scale);
                if (mode == 0) {
                    int hh = n >> 6, d = n & 63;
                    Qb[(((size_t)bb * NH + hh) * SEQ + s) * HDIM + d] = val;
                } else if (mode == 1) {
                    int nk = n - NQ; int kv = nk >> 6, d = nk & 63;
                    Kb[(((size_t)bb * NKVH + kv) * SEQ + s) * HDIM + d] = val;
                } else {
                    int nv = n - NQ - NKV; int kv = nv >> 6, d = nv & 63;
                    Vt[(((size_t)bb * NKVH + kv) * HDIM + d) * SEQ + s] = val;
                }
            }
        }
    }
}

// ---------------------------------------------------------------------------
// Kernel 2: flash attention, swapped-operand 32x32, LDS-staged K/V.
// Block = 128 q-rows of one (b,h); 4 waves x 32 q-rows. KV tile = 64 keys.
// K staged via global_load_lds w/ source pre-swizzle (XOR (row&7)<<4);
// V staged via reg->ds_write with key bits2<->3 permutation + same XOR, so
// PV V-fragments are single ds_read_b128 and P stays in natural reg order.
// Double-buffered (32KB LDS), one barrier/tile; loads for t+1 issued before
// compute of t.  Q comes in pre-scaled by (1/8)*log2(e); softmax in exp2
// domain with defer-max (THR=8).
// ---------------------------------------------------------------------------
__global__ __launch_bounds__(256, 4)
void attn(const __bf16* __restrict__ Qb,
          const __bf16* __restrict__ Kb,
          const __bf16* __restrict__ Vt,
          float* __restrict__ out)
{
    __shared__ char lds[32768];   // [buf][K 8KB | V 8KB] x2

    int qt = blockIdx.x;          // 0..15
    int bh = blockIdx.y;          // 0..63
    int b = bh >> 5, h = bh & 31;
    int kvh = h >> 2;             // REP = 4
    int tid = threadIdx.x, wave = tid >> 6, lane = tid & 63;
    int ql = lane & 31, hi = lane >> 5;
    int q0 = qt * 128 + wave * 32;

    const __bf16* Qp = Qb + (size_t)(b * NH + h) * SEQ * HDIM;
    const char*   Kp = (const char*)(Kb + (size_t)(b * NKVH + kvh) * SEQ * HDIM);
    const char*   Vp = (const char*)(Vt + (size_t)(b * NKVH + kvh) * HDIM * SEQ);

    // Q^T B-operand fragments
    bf16x8 qf[4];
    #pragma unroll
    for (int f = 0; f < 4; ++f)
        qf[f] = *reinterpret_cast<const bf16x8*>(Qp + (size_t)(q0 + ql) * HDIM + f * 16 + hi * 8);

    // ---- staging constants ----
    int Mq = (ql & 7) << 4;
    // K gload chunks: this wave stages chunks j0=wave, j1=wave+4 (1KB each).
    // LDS linear pos = j*1024 + lane*16 -> row = j*8+(lane>>3), stored col =
    // (lane&7)*16; global src col = stored ^ ((row&7)<<4).
    int kgoff0 = wave * 1024 + ((lane >> 3) << 7) + (((lane & 7) ^ (lane >> 3)) << 4);
    int kgoff1 = kgoff0 + 4096;
    int kdst0 = wave * 1024;             // + bufbase (wave-uniform)
    int kdst1 = kdst0 + 4096;
    // V stage: row d = wave*16 + (lane>>2), 32B at key-chunk c = lane&3
    int vd = wave * 16 + (lane >> 2);
    int vc = lane & 3;
    size_t vgoff = (size_t)vd * (SEQ * 2) + vc * 32;     // + kt*128
    int Mv = (vd & 7) << 4;
    int vwoffA = 8192 + vd * 128 + ((vc * 32) ^ Mv);     // + bufbase
    // ds_read offsets
    int koff[8], voff[8];
    #pragma unroll
    for (int kb = 0; kb < 2; ++kb)
        #pragma unroll
        for (int f = 0; f < 4; ++f)
            koff[kb * 4 + f] = (kb * 32 + ql) * 128 + ((f * 32 + hi * 16) ^ Mq);
    #pragma unroll
    for (int dh = 0; dh < 2; ++dh)
        #pragma unroll
        for (int ks = 0; ks < 4; ++ks)
            voff[dh * 4 + ks] = 8192 + (dh * 32 + ql) * 128 + ((ks * 32 + hi * 16) ^ Mq);

    f32x16 accO0 = {}, accO1 = {};   // O^T[d][q]
    float m_run = -1e30f, l_run = 0.0f;

    bf16x8 v0r, v1r;                 // V stage regs (issue-early, write-late)

    // ---- prologue: stage tile 0 into buf 0 ----
    gload_lds16(Kp + kgoff0, lds + kdst0);
    gload_lds16(Kp + kgoff1, lds + kdst1);
    {
        const char* gv = Vp + vgoff;
        v0r = *reinterpret_cast<const bf16x8*>(gv);
        v1r = *reinterpret_cast<const bf16x8*>(gv + 16);
        bf16x8 cA = __builtin_shufflevector(v0r, v1r, 0, 1, 2, 3, 8, 9, 10, 11);
        bf16x8 cB = __builtin_shufflevector(v0r, v1r, 4, 5, 6, 7, 12, 13, 14, 15);
        *reinterpret_cast<bf16x8*>(lds + vwoffA)        = cA;
        *reinterpret_cast<bf16x8*>(lds + (vwoffA ^ 16)) = cB;
    }
    __syncthreads();

    for (int kt = 0; kt < NT; ++kt) {
        int bufb  = (kt & 1) << 14;
        int nbufb = bufb ^ 16384;
        bool more = (kt + 1 < NT);
        if (more) {
            const char* gk = Kp + (size_t)(kt + 1) * 8192;
            gload_lds16(gk + kgoff0, lds + nbufb + kdst0);
            gload_lds16(gk + kgoff1, lds + nbufb + kdst1);
            const char* gv = Vp + vgoff + (size_t)(kt + 1) * 128;
            v0r = *reinterpret_cast<const bf16x8*>(gv);
            v1r = *reinterpret_cast<const bf16x8*>(gv + 16);
        }
        const char* Kl = lds + bufb;
        // ---- S^T = K . Q^T ----
        f32x16 s0 = {}, s1 = {};
        __builtin_amdgcn_s_setprio(1);
        {
            bf16x8 kf0 = *reinterpret_cast<const bf16x8*>(Kl + koff[0]);
            bf16x8 kf1 = *reinterpret_cast<const bf16x8*>(Kl + koff[1]);
            bf16x8 kf2 = *reinterpret_cast<const bf16x8*>(Kl + koff[2]);
            bf16x8 kf3 = *reinterpret_cast<const bf16x8*>(Kl + koff[3]);
            s0 = __builtin_amdgcn_mfma_f32_32x32x16_bf16(kf0, qf[0], s0, 0, 0, 0);
            s0 = __builtin_amdgcn_mfma_f32_32x32x16_bf16(kf1, qf[1], s0, 0, 0, 0);
            s0 = __builtin_amdgcn_mfma_f32_32x32x16_bf16(kf2, qf[2], s0, 0, 0, 0);
            s0 = __builtin_amdgcn_mfma_f32_32x32x16_bf16(kf3, qf[3], s0, 0, 0, 0);
            bf16x8 kf4 = *reinterpret_cast<const bf16x8*>(Kl + koff[4]);
            bf16x8 kf5 = *reinterpret_cast<const bf16x8*>(Kl + koff[5]);
            bf16x8 kf6 = *reinterpret_cast<const bf16x8*>(Kl + koff[6]);
            bf16x8 kf7 = *reinterpret_cast<const bf16x8*>(Kl + koff[7]);
            s1 = __builtin_amdgcn_mfma_f32_32x32x16_bf16(kf4, qf[0], s1, 0, 0, 0);
            s1 = __builtin_amdgcn_mfma_f32_32x32x16_bf16(kf5, qf[1], s1, 0, 0, 0);
            s1 = __builtin_amdgcn_mfma_f32_32x32x16_bf16(kf6, qf[2], s1, 0, 0, 0);
            s1 = __builtin_amdgcn_mfma_f32_32x32x16_bf16(kf7, qf[3], s1, 0, 0, 0);
        }
        __builtin_amdgcn_s_setprio(0);
        // ---- online softmax (exp2 domain; scale pre-folded into Q) ----
        float tm[8];
        #pragma unroll
        for (int r = 0; r < 8; ++r)
            tm[r] = fmaxf(fmaxf(s0[r], s0[r + 8]), fmaxf(s1[r], s1[r + 8]));
        #pragma unroll
        for (int st = 4; st > 0; st >>= 1)
            #pragma unroll
            for (int r = 0; r < st; ++r) tm[r] = fmaxf(tm[r], tm[r + st]);
        float mt = fmaxf(tm[0], __shfl_xor(tm[0], 32));
        if (!__all(mt <= m_run + 8.0f)) {          // defer-max (T13)
            float mn = fmaxf(m_run, mt);
            float alpha = __builtin_amdgcn_exp2f(m_run - mn);
            m_run = mn;
            l_run *= alpha;
            accO0 *= alpha;
            accO1 *= alpha;
        }
        #pragma unroll
        for (int r = 0; r < 16; ++r) {
            s0[r] = __builtin_amdgcn_exp2f(s0[r] - m_run);
            s1[r] = __builtin_amdgcn_exp2f(s1[r] - m_run);
        }
        float ts[8];
        #pragma unroll
        for (int r = 0; r < 8; ++r)
            ts[r] = (s0[r] + s0[r + 8]) + (s1[r] + s1[r + 8]);
        #pragma unroll
        for (int st = 4; st > 0; st >>= 1)
            #pragma unroll
            for (int r = 0; r < st; ++r) ts[r] += ts[r + st];
        l_run += ts[0] + __shfl_xor(ts[0], 32);
        // ---- pack P fragments (natural register order) ----
        bf16x8 pfr[4];
        #pragma unroll
        for (int ks = 0; ks < 4; ++ks) {
            u32x4 wv;
            #pragma unroll
            for (int tt = 0; tt < 4; ++tt) {
                float a = (ks < 2) ? s0[(ks & 1) * 8 + 2 * tt]     : s1[(ks & 1) * 8 + 2 * tt];
                float c = (ks < 2) ? s0[(ks & 1) * 8 + 2 * tt + 1] : s1[(ks & 1) * 8 + 2 * tt + 1];
                wv[tt] = pack2bf(a, c);
            }
            pfr[ks] = __builtin_bit_cast(bf16x8, wv);
        }
        // ---- O^T += V~ . P~ ----
        __builtin_amdgcn_s_setprio(1);
        #pragma unroll
        for (int ks = 0; ks < 4; ++ks) {
            bf16x8 vv0 = *reinterpret_cast<const bf16x8*>(Kl + voff[ks]);
            bf16x8 vv1 = *reinterpret_cast<const bf16x8*>(Kl + voff[4 + ks]);
            accO0 = __builtin_amdgcn_mfma_f32_32x32x16_bf16(vv0, pfr[ks], accO0, 0, 0, 0);
            accO1 = __builtin_amdgcn_mfma_f32_32x32x16_bf16(vv1, pfr[ks], accO1, 0, 0, 0);
        }
        __builtin_amdgcn_s_setprio(0);
        // ---- write staged V regs into next buffer, then swap ----
        if (more) {
            bf16x8 cA = __builtin_shufflevector(v0r, v1r, 0, 1, 2, 3, 8, 9, 10, 11);
            bf16x8 cB = __builtin_shufflevector(v0r, v1r, 4, 5, 6, 7, 12, 13, 14, 15);
            *reinterpret_cast<bf16x8*>(lds + nbufb + vwoffA)        = cA;
            *reinterpret_cast<bf16x8*>(lds + nbufb + (vwoffA ^ 16)) = cB;
        }
        __syncthreads();
    }
    // ---- epilogue: lane q = ql; d = (r&3) + 8*(r>>2) + 4*hi (+32 for accO1)
    float inv = 1.0f / l_run;
    float* op = out + ((size_t)b * SEQ + q0 + ql) * DMODEL + h * HDIM;
    #pragma unroll
    for (int G = 0; G < 4; ++G) {
        f32x4 o0 = { accO0[4 * G + 0] * inv, accO0[4 * G + 1] * inv,
                     accO0[4 * G + 2] * inv, accO0[4 * G + 3] * inv };
        f32x4 o1 = { accO1[4 * G + 0] * inv, accO1[4 * G + 1] * inv,
                     accO1[4 * G + 2] * inv, accO1[4 * G + 3] * inv };
        *reinterpret_cast<f32x4*>(op + 8 * G + 4 * hi)      = o0;
        *reinterpret_cast<f32x4*>(op + 32 + 8 * G + 4 * hi) = o1;
    }
}

// ---------------------------------------------------------------------------
extern "C" void kernel_launch(void* const* d_in, const int* in_sizes, int n_in,
                              void* d_out, int out_size, void* d_ws, size_t ws_size,
                              hipStream_t stream)
{
    const float* hs = (const float*)d_in[0];
    const float* Wq = (const float*)d_in[1];
    const float* bq = (const float*)d_in[2];
    const float* Wk = (const float*)d_in[3];
    const float* bk = (const float*)d_in[4];
    const float* Wv = (const float*)d_in[5];
    const float* bv = (const float*)d_in[6];
    float* out = (float*)d_out;

    char* ws = (char*)d_ws;
    __bf16* Wt = (__bf16*)(ws);                                   // 12,582,912 B
    __bf16* Qb = (__bf16*)(ws + 12582912);                        // 16,777,216 B
    __bf16* Kb = (__bf16*)(ws + 12582912 + 16777216);             //  4,194,304 B
    __bf16* Vt = (__bf16*)(ws + 12582912 + 16777216 + 4194304);   //  4,194,304 B

    hipLaunchKernelGGL(transpose_w, dim3(32, 48), dim3(256), 0, stream, Wq, Wk, Wv, Wt);
    hipLaunchKernelGGL(qkv_gemm,    dim3(24, 32), dim3(256), 0, stream, hs, Wt, bq, bk, bv, Qb, Kb, Vt);
    hipLaunchKernelGGL(attn,        dim3(16, 64), dim3(256), 0, stream, Qb, Kb, Vt, out);
}

// Round 6
// 199.238 us; speedup vs baseline: 3.1416x; 1.3542x over previous
//
#include <hip/hip_runtime.h>
#include <hip/hip_bf16.h>

#define NH 32
#define NKVH 8
#define DMODEL 2048
#define HDIM 64
#define NB 2
#define SEQ 2048
#define MROWS (NB*SEQ)      // 4096
#define NQ 2048
#define NKV 512
#define NTOT 3072
#define NT (SEQ/64)         // 32 kv tiles

typedef __bf16 bf16x4 __attribute__((ext_vector_type(4)));
typedef __bf16 bf16x8 __attribute__((ext_vector_type(8)));
typedef float  f32x4  __attribute__((ext_vector_type(4)));
typedef float  f32x16 __attribute__((ext_vector_type(16)));
typedef unsigned u32x4 __attribute__((ext_vector_type(4)));

__device__ inline __bf16 f2bf(float f) {
    unsigned u = __builtin_bit_cast(unsigned, f);
    u += 0x7fff + ((u >> 16) & 1);               // RNE
    unsigned short s = (unsigned short)(u >> 16);
    return __builtin_bit_cast(__bf16, s);
}

// pack two f32 -> one u32 holding 2x bf16 (lo = a, hi = b); plain bit-ops
__device__ inline unsigned pack2bf(float a, float b) {
    unsigned ua = __builtin_bit_cast(unsigned, a);
    ua += 0x7fff + ((ua >> 16) & 1);
    unsigned ub = __builtin_bit_cast(unsigned, b);
    ub += 0x7fff + ((ub >> 16) & 1);
    return (ua >> 16) | (ub & 0xffff0000u);
}

__device__ inline void gload_lds16(const void* g, void* l) {
    __builtin_amdgcn_global_load_lds(
        (const __attribute__((address_space(1))) void*)g,
        (__attribute__((address_space(3))) void*)l, 16, 0, 0);
}

// ---------------------------------------------------------------------------
// Kernel 0a: hidden fp32 [4096][2048] -> bf16 (RNE), contiguous
// ---------------------------------------------------------------------------
__global__ __launch_bounds__(256)
void cvt_hs(const float* __restrict__ Hs, __bf16* __restrict__ Ab)
{
    size_t idx = ((size_t)blockIdx.x * 256 + threadIdx.x) * 8;
    f32x4 a = *reinterpret_cast<const f32x4*>(Hs + idx);
    f32x4 b = *reinterpret_cast<const f32x4*>(Hs + idx + 4);
    u32x4 w;
    w[0] = pack2bf(a[0], a[1]); w[1] = pack2bf(a[2], a[3]);
    w[2] = pack2bf(b[0], b[1]); w[3] = pack2bf(b[2], b[3]);
    *reinterpret_cast<u32x4*>((char*)Ab + idx * 2) = w;
}

// ---------------------------------------------------------------------------
// Kernel 0b: fuse Wq|Wk|Wv (fp32, [K][N]) -> Wt bf16 [3072][2048] (N-major)
// ---------------------------------------------------------------------------
__global__ __launch_bounds__(256)
void transpose_w(const float* __restrict__ Wq,
                 const float* __restrict__ Wk,
                 const float* __restrict__ Wv,
                 __bf16* __restrict__ Wt)
{
    __shared__ __bf16 tile[64][72];
    int k0 = blockIdx.x * 64;     // 32 tiles
    int n0 = blockIdx.y * 64;     // 48 tiles
    const float* Wsrc; int ncols; int nbase;
    if (n0 < NQ)            { Wsrc = Wq; ncols = NQ;  nbase = n0; }
    else if (n0 < NQ + NKV) { Wsrc = Wk; ncols = NKV; nbase = n0 - NQ; }
    else                    { Wsrc = Wv; ncols = NKV; nbase = n0 - NQ - NKV; }
    int t = threadIdx.x;
    int kl = t >> 2;
    int nc = (t & 3) * 16;
    const float* src = Wsrc + (size_t)(k0 + kl) * ncols + nbase + nc;
    #pragma unroll
    for (int i = 0; i < 4; ++i) {
        f32x4 v = *reinterpret_cast<const f32x4*>(src + i * 4);
        #pragma unroll
        for (int e = 0; e < 4; ++e) tile[kl][nc + i * 4 + e] = f2bf(v[e]);
    }
    __syncthreads();
    int nl = t >> 2;
    int kc = (t & 3) * 16;
    bf16x8 o0, o1;
    #pragma unroll
    for (int i = 0; i < 8; ++i) o0[i] = tile[kc + i][nl];
    #pragma unroll
    for (int i = 0; i < 8; ++i) o1[i] = tile[kc + 8 + i][nl];
    __bf16* dst = Wt + (size_t)(n0 + nl) * DMODEL + k0 + kc;
    *reinterpret_cast<bf16x8*>(dst)     = o0;
    *reinterpret_cast<bf16x8*>(dst + 8) = o1;
}

// ---------------------------------------------------------------------------
// Kernel 1: QKV projection GEMM (m97 structure).  A = Ab bf16 [4096][2048],
// B = Wt bf16 [3072][2048] (row n, contiguous k).  C tiled 128x128, BK=64.
// Staging: global_load_lds width-16, linear LDS dest, SOURCE pre-swizzled
// (chunk ^= row&7); ds_read_b128 with matching XOR -> conflict-free.
// Outputs: Q [B,NH,S,64] PRE-SCALED by (1/8)*log2(e), K [B,NKVH,S,64],
//          Vt [B,NKVH,64,S]  (all bf16, +bias)
// ---------------------------------------------------------------------------
#define BM 128
#define BN 128
#define BK 64

__global__ __launch_bounds__(256)
void qkv_gemm(const __bf16* __restrict__ Ab,
              const __bf16* __restrict__ Wt,
              const float* __restrict__ bq,
              const float* __restrict__ bk,
              const float* __restrict__ bv,
              __bf16* __restrict__ Qb,
              __bf16* __restrict__ Kb,
              __bf16* __restrict__ Vt)
{
    __shared__ char lds[32768];   // A 16KB | B 16KB

    // bijective XCD swizzle: 768 blocks, 768 % 8 == 0
    int bid = blockIdx.x;
    int wg = (bid & 7) * 96 + (bid >> 3);
    int n0 = (wg % 24) * BN;
    int m0 = (wg / 24) * BM;

    int t = threadIdx.x;
    int wave = t >> 6, lane = t & 63;
    int g = lane >> 4, lh = lane & 15;
    int wr = wave >> 1, wc = wave & 1;

    // staging: inst i covers rows [i*32 + wave*8 + (lane>>3)], chunk lane&7
    int srow = wave * 8 + (lane >> 3);
    int schunk = (lane & 7) ^ (lane >> 3);       // source pre-swizzle
    const char* Asrc = (const char*)Ab + (size_t)(m0 + srow) * 4096 + schunk * 16;
    const char* Bsrc = (const char*)Wt + (size_t)(n0 + srow) * 4096 + schunk * 16;
    int dstw = wave * 1024;

    f32x4 acc[4][4] = {};

    for (int k0 = 0; k0 < DMODEL * 2; k0 += BK * 2) {   // byte offset in K
        #pragma unroll
        for (int i = 0; i < 4; ++i)
            gload_lds16(Asrc + (size_t)i * 32 * 4096 + k0, lds + i * 4096 + dstw);
        #pragma unroll
        for (int i = 0; i < 4; ++i)
            gload_lds16(Bsrc + (size_t)i * 32 * 4096 + k0, lds + 16384 + i * 4096 + dstw);
        __syncthreads();
        #pragma unroll
        for (int kk = 0; kk < 2; ++kk) {
            bf16x8 af[4], bfr[4];
            #pragma unroll
            for (int mi = 0; mi < 4; ++mi) {
                int row = wr * 64 + mi * 16 + lh;
                int byte = row * 128 + (((kk * 4 + g) ^ (lh & 7)) << 4);
                af[mi] = *reinterpret_cast<const bf16x8*>(lds + byte);
            }
            #pragma unroll
            for (int ni = 0; ni < 4; ++ni) {
                int row = wc * 64 + ni * 16 + lh;
                int byte = row * 128 + (((kk * 4 + g) ^ (lh & 7)) << 4);
                bfr[ni] = *reinterpret_cast<const bf16x8*>(lds + 16384 + byte);
            }
            #pragma unroll
            for (int mi = 0; mi < 4; ++mi)
                #pragma unroll
                for (int ni = 0; ni < 4; ++ni)
                    acc[mi][ni] = __builtin_amdgcn_mfma_f32_16x16x32_bf16(af[mi], bfr[ni], acc[mi][ni], 0, 0, 0);
        }
        __syncthreads();
    }

    // --- epilogue: bias + route to Q / K / Vt ---
    int mode = (n0 < NQ) ? 0 : (n0 < NQ + NKV ? 1 : 2);
    const float* bias = (mode == 0) ? bq : (mode == 1 ? bk : bv);
    int nsub = (mode == 0) ? 0 : (mode == 1 ? NQ : NQ + NKV);
    float scale = (mode == 0) ? 0.18033688011112042f : 1.0f;  // (1/8)*log2(e)

    float biasv[4];
    #pragma unroll
    for (int ni = 0; ni < 4; ++ni)
        biasv[ni] = bias[n0 - nsub + wc * 64 + ni * 16 + lh];

    #pragma unroll
    for (int mi = 0; mi < 4; ++mi) {
        #pragma unroll
        for (int j = 0; j < 4; ++j) {
            int m = m0 + wr * 64 + mi * 16 + 4 * g + j;
            int bb = m >> 11, s = m & (SEQ - 1);
            #pragma unroll
            for (int ni = 0; ni < 4; ++ni) {
                int n = n0 + wc * 64 + ni * 16 + lh;
                __bf16 val = f2bf((acc[mi][ni][j] + biasv[ni]) * scale);
                if (mode == 0) {
                    int hh = n >> 6, d = n & 63;
                    Qb[(((size_t)bb * NH + hh) * SEQ + s) * HDIM + d] = val;
                } else if (mode == 1) {
                    int nk = n - NQ; int kv = nk >> 6, d = nk & 63;
                    Kb[(((size_t)bb * NKVH + kv) * SEQ + s) * HDIM + d] = val;
                } else {
                    int nv = n - NQ - NKV; int kv = nv >> 6, d = nv & 63;
                    Vt[(((size_t)bb * NKVH + kv) * HDIM + d) * SEQ + s] = val;
                }
            }
        }
    }
}

// ---------------------------------------------------------------------------
// Kernel 2: flash attention, swapped-operand 32x32, LDS-staged K/V.
// (unchanged from R5 — see comments there)
// ---------------------------------------------------------------------------
__global__ __launch_bounds__(256, 4)
void attn(const __bf16* __restrict__ Qb,
          const __bf16* __restrict__ Kb,
          const __bf16* __restrict__ Vt,
          float* __restrict__ out)
{
    __shared__ char lds[32768];   // [buf][K 8KB | V 8KB] x2

    int qt = blockIdx.x;          // 0..15
    int bh = blockIdx.y;          // 0..63
    int b = bh >> 5, h = bh & 31;
    int kvh = h >> 2;             // REP = 4
    int tid = threadIdx.x, wave = tid >> 6, lane = tid & 63;
    int ql = lane & 31, hi = lane >> 5;
    int q0 = qt * 128 + wave * 32;

    const __bf16* Qp = Qb + (size_t)(b * NH + h) * SEQ * HDIM;
    const char*   Kp = (const char*)(Kb + (size_t)(b * NKVH + kvh) * SEQ * HDIM);
    const char*   Vp = (const char*)(Vt + (size_t)(b * NKVH + kvh) * HDIM * SEQ);

    bf16x8 qf[4];
    #pragma unroll
    for (int f = 0; f < 4; ++f)
        qf[f] = *reinterpret_cast<const bf16x8*>(Qp + (size_t)(q0 + ql) * HDIM + f * 16 + hi * 8);

    int Mq = (ql & 7) << 4;
    int kgoff0 = wave * 1024 + ((lane >> 3) << 7) + (((lane & 7) ^ (lane >> 3)) << 4);
    int kgoff1 = kgoff0 + 4096;
    int kdst0 = wave * 1024;
    int kdst1 = kdst0 + 4096;
    int vd = wave * 16 + (lane >> 2);
    int vc = lane & 3;
    size_t vgoff = (size_t)vd * (SEQ * 2) + vc * 32;
    int Mv = (vd & 7) << 4;
    int vwoffA = 8192 + vd * 128 + ((vc * 32) ^ Mv);
    int koff[8], voff[8];
    #pragma unroll
    for (int kb = 0; kb < 2; ++kb)
        #pragma unroll
        for (int f = 0; f < 4; ++f)
            koff[kb * 4 + f] = (kb * 32 + ql) * 128 + ((f * 32 + hi * 16) ^ Mq);
    #pragma unroll
    for (int dh = 0; dh < 2; ++dh)
        #pragma unroll
        for (int ks = 0; ks < 4; ++ks)
            voff[dh * 4 + ks] = 8192 + (dh * 32 + ql) * 128 + ((ks * 32 + hi * 16) ^ Mq);

    f32x16 accO0 = {}, accO1 = {};
    float m_run = -1e30f, l_run = 0.0f;

    bf16x8 v0r, v1r;

    gload_lds16(Kp + kgoff0, lds + kdst0);
    gload_lds16(Kp + kgoff1, lds + kdst1);
    {
        const char* gv = Vp + vgoff;
        v0r = *reinterpret_cast<const bf16x8*>(gv);
        v1r = *reinterpret_cast<const bf16x8*>(gv + 16);
        bf16x8 cA = __builtin_shufflevector(v0r, v1r, 0, 1, 2, 3, 8, 9, 10, 11);
        bf16x8 cB = __builtin_shufflevector(v0r, v1r, 4, 5, 6, 7, 12, 13, 14, 15);
        *reinterpret_cast<bf16x8*>(lds + vwoffA)        = cA;
        *reinterpret_cast<bf16x8*>(lds + (vwoffA ^ 16)) = cB;
    }
    __syncthreads();

    for (int kt = 0; kt < NT; ++kt) {
        int bufb  = (kt & 1) << 14;
        int nbufb = bufb ^ 16384;
        bool more = (kt + 1 < NT);
        if (more) {
            const char* gk = Kp + (size_t)(kt + 1) * 8192;
            gload_lds16(gk + kgoff0, lds + nbufb + kdst0);
            gload_lds16(gk + kgoff1, lds + nbufb + kdst1);
            const char* gv = Vp + vgoff + (size_t)(kt + 1) * 128;
            v0r = *reinterpret_cast<const bf16x8*>(gv);
            v1r = *reinterpret_cast<const bf16x8*>(gv + 16);
        }
        const char* Kl = lds + bufb;
        f32x16 s0 = {}, s1 = {};
        __builtin_amdgcn_s_setprio(1);
        {
            bf16x8 kf0 = *reinterpret_cast<const bf16x8*>(Kl + koff[0]);
            bf16x8 kf1 = *reinterpret_cast<const bf16x8*>(Kl + koff[1]);
            bf16x8 kf2 = *reinterpret_cast<const bf16x8*>(Kl + koff[2]);
            bf16x8 kf3 = *reinterpret_cast<const bf16x8*>(Kl + koff[3]);
            s0 = __builtin_amdgcn_mfma_f32_32x32x16_bf16(kf0, qf[0], s0, 0, 0, 0);
            s0 = __builtin_amdgcn_mfma_f32_32x32x16_bf16(kf1, qf[1], s0, 0, 0, 0);
            s0 = __builtin_amdgcn_mfma_f32_32x32x16_bf16(kf2, qf[2], s0, 0, 0, 0);
            s0 = __builtin_amdgcn_mfma_f32_32x32x16_bf16(kf3, qf[3], s0, 0, 0, 0);
            bf16x8 kf4 = *reinterpret_cast<const bf16x8*>(Kl + koff[4]);
            bf16x8 kf5 = *reinterpret_cast<const bf16x8*>(Kl + koff[5]);
            bf16x8 kf6 = *reinterpret_cast<const bf16x8*>(Kl + koff[6]);
            bf16x8 kf7 = *reinterpret_cast<const bf16x8*>(Kl + koff[7]);
            s1 = __builtin_amdgcn_mfma_f32_32x32x16_bf16(kf4, qf[0], s1, 0, 0, 0);
            s1 = __builtin_amdgcn_mfma_f32_32x32x16_bf16(kf5, qf[1], s1, 0, 0, 0);
            s1 = __builtin_amdgcn_mfma_f32_32x32x16_bf16(kf6, qf[2], s1, 0, 0, 0);
            s1 = __builtin_amdgcn_mfma_f32_32x32x16_bf16(kf7, qf[3], s1, 0, 0, 0);
        }
        __builtin_amdgcn_s_setprio(0);
        float tm[8];
        #pragma unroll
        for (int r = 0; r < 8; ++r)
            tm[r] = fmaxf(fmaxf(s0[r], s0[r + 8]), fmaxf(s1[r], s1[r + 8]));
        #pragma unroll
        for (int st = 4; st > 0; st >>= 1)
            #pragma unroll
            for (int r = 0; r < st; ++r) tm[r] = fmaxf(tm[r], tm[r + st]);
        float mt = fmaxf(tm[0], __shfl_xor(tm[0], 32));
        if (!__all(mt <= m_run + 8.0f)) {          // defer-max (T13)
            float mn = fmaxf(m_run, mt);
            float alpha = __builtin_amdgcn_exp2f(m_run - mn);
            m_run = mn;
            l_run *= alpha;
            accO0 *= alpha;
            accO1 *= alpha;
        }
        #pragma unroll
        for (int r = 0; r < 16; ++r) {
            s0[r] = __builtin_amdgcn_exp2f(s0[r] - m_run);
            s1[r] = __builtin_amdgcn_exp2f(s1[r] - m_run);
        }
        float ts[8];
        #pragma unroll
        for (int r = 0; r < 8; ++r)
            ts[r] = (s0[r] + s0[r + 8]) + (s1[r] + s1[r + 8]);
        #pragma unroll
        for (int st = 4; st > 0; st >>= 1)
            #pragma unroll
            for (int r = 0; r < st; ++r) ts[r] += ts[r + st];
        l_run += ts[0] + __shfl_xor(ts[0], 32);
        bf16x8 pfr[4];
        #pragma unroll
        for (int ks = 0; ks < 4; ++ks) {
            u32x4 wv;
            #pragma unroll
            for (int tt = 0; tt < 4; ++tt) {
                float a = (ks < 2) ? s0[(ks & 1) * 8 + 2 * tt]     : s1[(ks & 1) * 8 + 2 * tt];
                float c = (ks < 2) ? s0[(ks & 1) * 8 + 2 * tt + 1] : s1[(ks & 1) * 8 + 2 * tt + 1];
                wv[tt] = pack2bf(a, c);
            }
            pfr[ks] = __builtin_bit_cast(bf16x8, wv);
        }
        __builtin_amdgcn_s_setprio(1);
        #pragma unroll
        for (int ks = 0; ks < 4; ++ks) {
            bf16x8 vv0 = *reinterpret_cast<const bf16x8*>(Kl + voff[ks]);
            bf16x8 vv1 = *reinterpret_cast<const bf16x8*>(Kl + voff[4 + ks]);
            accO0 = __builtin_amdgcn_mfma_f32_32x32x16_bf16(vv0, pfr[ks], accO0, 0, 0, 0);
            accO1 = __builtin_amdgcn_mfma_f32_32x32x16_bf16(vv1, pfr[ks], accO1, 0, 0, 0);
        }
        __builtin_amdgcn_s_setprio(0);
        if (more) {
            bf16x8 cA = __builtin_shufflevector(v0r, v1r, 0, 1, 2, 3, 8, 9, 10, 11);
            bf16x8 cB = __builtin_shufflevector(v0r, v1r, 4, 5, 6, 7, 12, 13, 14, 15);
            *reinterpret_cast<bf16x8*>(lds + nbufb + vwoffA)        = cA;
            *reinterpret_cast<bf16x8*>(lds + nbufb + (vwoffA ^ 16)) = cB;
        }
        __syncthreads();
    }
    float inv = 1.0f / l_run;
    float* op = out + ((size_t)b * SEQ + q0 + ql) * DMODEL + h * HDIM;
    #pragma unroll
    for (int G = 0; G < 4; ++G) {
        f32x4 o0 = { accO0[4 * G + 0] * inv, accO0[4 * G + 1] * inv,
                     accO0[4 * G + 2] * inv, accO0[4 * G + 3] * inv };
        f32x4 o1 = { accO1[4 * G + 0] * inv, accO1[4 * G + 1] * inv,
                     accO1[4 * G + 2] * inv, accO1[4 * G + 3] * inv };
        *reinterpret_cast<f32x4*>(op + 8 * G + 4 * hi)      = o0;
        *reinterpret_cast<f32x4*>(op + 32 + 8 * G + 4 * hi) = o1;
    }
}

// ---------------------------------------------------------------------------
extern "C" void kernel_launch(void* const* d_in, const int* in_sizes, int n_in,
                              void* d_out, int out_size, void* d_ws, size_t ws_size,
                              hipStream_t stream)
{
    const float* hs = (const float*)d_in[0];
    const float* Wq = (const float*)d_in[1];
    const float* bq = (const float*)d_in[2];
    const float* Wk = (const float*)d_in[3];
    const float* bk = (const float*)d_in[4];
    const float* Wv = (const float*)d_in[5];
    const float* bv = (const float*)d_in[6];
    float* out = (float*)d_out;

    char* ws = (char*)d_ws;
    __bf16* Wt = (__bf16*)(ws);                                   // 12,582,912 B
    __bf16* Ab = (__bf16*)(ws + 12582912);                        // 16,777,216 B
    __bf16* Qb = (__bf16*)(ws + 12582912 + 16777216);             // 16,777,216 B
    __bf16* Kb = (__bf16*)(ws + 12582912 + 2*16777216);           //  4,194,304 B
    __bf16* Vt = (__bf16*)(ws + 12582912 + 2*16777216 + 4194304); //  4,194,304 B

    hipLaunchKernelGGL(cvt_hs,      dim3(4096),   dim3(256), 0, stream, hs, Ab);
    hipLaunchKernelGGL(transpose_w, dim3(32, 48), dim3(256), 0, stream, Wq, Wk, Wv, Wt);
    hipLaunchKernelGGL(qkv_gemm,    dim3(768),    dim3(256), 0, stream, Ab, Wt, bq, bk, bv, Qb, Kb, Vt);
    hipLaunchKernelGGL(attn,        dim3(16, 64), dim3(256), 0, stream, Qb, Kb, Vt, out);
}

// Round 7
// 189.361 us; speedup vs baseline: 3.3054x; 1.0522x over previous
//
#include <hip/hip_runtime.h>
#include <hip/hip_bf16.h>

#define NH 32
#define NKVH 8
#define DMODEL 2048
#define HDIM 64
#define NB 2
#define SEQ 2048
#define MROWS (NB*SEQ)      // 4096
#define NQ 2048
#define NKV 512
#define NTOT 3072
#define NT (SEQ/64)         // 32 kv tiles

typedef __bf16 bf16x4 __attribute__((ext_vector_type(4)));
typedef __bf16 bf16x8 __attribute__((ext_vector_type(8)));
typedef float  f32x4  __attribute__((ext_vector_type(4)));
typedef float  f32x16 __attribute__((ext_vector_type(16)));
typedef unsigned u32x4 __attribute__((ext_vector_type(4)));

__device__ inline __bf16 f2bf(float f) {
    unsigned u = __builtin_bit_cast(unsigned, f);
    u += 0x7fff + ((u >> 16) & 1);               // RNE
    unsigned short s = (unsigned short)(u >> 16);
    return __builtin_bit_cast(__bf16, s);
}

// pack two f32 -> one u32 holding 2x bf16 (lo = a, hi = b); plain bit-ops
__device__ inline unsigned pack2bf(float a, float b) {
    unsigned ua = __builtin_bit_cast(unsigned, a);
    ua += 0x7fff + ((ua >> 16) & 1);
    unsigned ub = __builtin_bit_cast(unsigned, b);
    ub += 0x7fff + ((ub >> 16) & 1);
    return (ua >> 16) | (ub & 0xffff0000u);
}

__device__ inline void gload_lds16(const void* g, void* l) {
    __builtin_amdgcn_global_load_lds(
        (const __attribute__((address_space(1))) void*)g,
        (__attribute__((address_space(3))) void*)l, 16, 0, 0);
}

// ---------------------------------------------------------------------------
// Kernel 0a: hidden fp32 [4096][2048] -> bf16 (RNE), contiguous
// ---------------------------------------------------------------------------
__global__ __launch_bounds__(256)
void cvt_hs(const float* __restrict__ Hs, __bf16* __restrict__ Ab)
{
    size_t idx = ((size_t)blockIdx.x * 256 + threadIdx.x) * 8;
    f32x4 a = *reinterpret_cast<const f32x4*>(Hs + idx);
    f32x4 b = *reinterpret_cast<const f32x4*>(Hs + idx + 4);
    u32x4 w;
    w[0] = pack2bf(a[0], a[1]); w[1] = pack2bf(a[2], a[3]);
    w[2] = pack2bf(b[0], b[1]); w[3] = pack2bf(b[2], b[3]);
    *reinterpret_cast<u32x4*>((char*)Ab + idx * 2) = w;
}

// ---------------------------------------------------------------------------
// Kernel 0b: fuse Wq|Wk|Wv (fp32, [K][N]) -> Wt bf16 [3072][2048] (N-major)
// ---------------------------------------------------------------------------
__global__ __launch_bounds__(256)
void transpose_w(const float* __restrict__ Wq,
                 const float* __restrict__ Wk,
                 const float* __restrict__ Wv,
                 __bf16* __restrict__ Wt)
{
    __shared__ __bf16 tile[64][72];
    int k0 = blockIdx.x * 64;     // 32 tiles
    int n0 = blockIdx.y * 64;     // 48 tiles
    const float* Wsrc; int ncols; int nbase;
    if (n0 < NQ)            { Wsrc = Wq; ncols = NQ;  nbase = n0; }
    else if (n0 < NQ + NKV) { Wsrc = Wk; ncols = NKV; nbase = n0 - NQ; }
    else                    { Wsrc = Wv; ncols = NKV; nbase = n0 - NQ - NKV; }
    int t = threadIdx.x;
    int kl = t >> 2;
    int nc = (t & 3) * 16;
    const float* src = Wsrc + (size_t)(k0 + kl) * ncols + nbase + nc;
    #pragma unroll
    for (int i = 0; i < 4; ++i) {
        f32x4 v = *reinterpret_cast<const f32x4*>(src + i * 4);
        #pragma unroll
        for (int e = 0; e < 4; ++e) tile[kl][nc + i * 4 + e] = f2bf(v[e]);
    }
    __syncthreads();
    int nl = t >> 2;
    int kc = (t & 3) * 16;
    bf16x8 o0, o1;
    #pragma unroll
    for (int i = 0; i < 8; ++i) o0[i] = tile[kc + i][nl];
    #pragma unroll
    for (int i = 0; i < 8; ++i) o1[i] = tile[kc + 8 + i][nl];
    __bf16* dst = Wt + (size_t)(n0 + nl) * DMODEL + k0 + kc;
    *reinterpret_cast<bf16x8*>(dst)     = o0;
    *reinterpret_cast<bf16x8*>(dst + 8) = o1;
}

// ---------------------------------------------------------------------------
// Kernel 1: QKV projection GEMM (m97 structure).  A = Ab bf16 [4096][2048],
// B = Wt bf16 [3072][2048].  C tiled 128x128, BK=64, global_load_lds staging
// with source pre-swizzle.  Outputs: Q (pre-scaled), K, Vt (bf16, +bias).
// ---------------------------------------------------------------------------
#define BM 128
#define BN 128
#define BK 64

__global__ __launch_bounds__(256)
void qkv_gemm(const __bf16* __restrict__ Ab,
              const __bf16* __restrict__ Wt,
              const float* __restrict__ bq,
              const float* __restrict__ bk,
              const float* __restrict__ bv,
              __bf16* __restrict__ Qb,
              __bf16* __restrict__ Kb,
              __bf16* __restrict__ Vt)
{
    __shared__ char lds[32768];   // A 16KB | B 16KB

    int bid = blockIdx.x;
    int wg = (bid & 7) * 96 + (bid >> 3);
    int n0 = (wg % 24) * BN;
    int m0 = (wg / 24) * BM;

    int t = threadIdx.x;
    int wave = t >> 6, lane = t & 63;
    int g = lane >> 4, lh = lane & 15;
    int wr = wave >> 1, wc = wave & 1;

    int srow = wave * 8 + (lane >> 3);
    int schunk = (lane & 7) ^ (lane >> 3);       // source pre-swizzle
    const char* Asrc = (const char*)Ab + (size_t)(m0 + srow) * 4096 + schunk * 16;
    const char* Bsrc = (const char*)Wt + (size_t)(n0 + srow) * 4096 + schunk * 16;
    int dstw = wave * 1024;

    f32x4 acc[4][4] = {};

    for (int k0 = 0; k0 < DMODEL * 2; k0 += BK * 2) {   // byte offset in K
        #pragma unroll
        for (int i = 0; i < 4; ++i)
            gload_lds16(Asrc + (size_t)i * 32 * 4096 + k0, lds + i * 4096 + dstw);
        #pragma unroll
        for (int i = 0; i < 4; ++i)
            gload_lds16(Bsrc + (size_t)i * 32 * 4096 + k0, lds + 16384 + i * 4096 + dstw);
        __syncthreads();
        #pragma unroll
        for (int kk = 0; kk < 2; ++kk) {
            bf16x8 af[4], bfr[4];
            #pragma unroll
            for (int mi = 0; mi < 4; ++mi) {
                int row = wr * 64 + mi * 16 + lh;
                int byte = row * 128 + (((kk * 4 + g) ^ (lh & 7)) << 4);
                af[mi] = *reinterpret_cast<const bf16x8*>(lds + byte);
            }
            #pragma unroll
            for (int ni = 0; ni < 4; ++ni) {
                int row = wc * 64 + ni * 16 + lh;
                int byte = row * 128 + (((kk * 4 + g) ^ (lh & 7)) << 4);
                bfr[ni] = *reinterpret_cast<const bf16x8*>(lds + 16384 + byte);
            }
            #pragma unroll
            for (int mi = 0; mi < 4; ++mi)
                #pragma unroll
                for (int ni = 0; ni < 4; ++ni)
                    acc[mi][ni] = __builtin_amdgcn_mfma_f32_16x16x32_bf16(af[mi], bfr[ni], acc[mi][ni], 0, 0, 0);
        }
        __syncthreads();
    }

    int mode = (n0 < NQ) ? 0 : (n0 < NQ + NKV ? 1 : 2);
    const float* bias = (mode == 0) ? bq : (mode == 1 ? bk : bv);
    int nsub = (mode == 0) ? 0 : (mode == 1 ? NQ : NQ + NKV);
    float scale = (mode == 0) ? 0.18033688011112042f : 1.0f;  // (1/8)*log2(e)

    float biasv[4];
    #pragma unroll
    for (int ni = 0; ni < 4; ++ni)
        biasv[ni] = bias[n0 - nsub + wc * 64 + ni * 16 + lh];

    #pragma unroll
    for (int mi = 0; mi < 4; ++mi) {
        #pragma unroll
        for (int j = 0; j < 4; ++j) {
            int m = m0 + wr * 64 + mi * 16 + 4 * g + j;
            int bb = m >> 11, s = m & (SEQ - 1);
            #pragma unroll
            for (int ni = 0; ni < 4; ++ni) {
                int n = n0 + wc * 64 + ni * 16 + lh;
                __bf16 val = f2bf((acc[mi][ni][j] + biasv[ni]) * scale);
                if (mode == 0) {
                    int hh = n >> 6, d = n & 63;
                    Qb[(((size_t)bb * NH + hh) * SEQ + s) * HDIM + d] = val;
                } else if (mode == 1) {
                    int nk = n - NQ; int kv = nk >> 6, d = nk & 63;
                    Kb[(((size_t)bb * NKVH + kv) * SEQ + s) * HDIM + d] = val;
                } else {
                    int nv = n - NQ - NKV; int kv = nv >> 6, d = nv & 63;
                    Vt[(((size_t)bb * NKVH + kv) * HDIM + d) * SEQ + s] = val;
                }
            }
        }
    }
}

// ---------------------------------------------------------------------------
// Kernel 2: flash attention, swapped-operand 32x32, LDS-staged K/V.
// R7: 32-key substeps (16-reg score buffer -> no AGPR round-trips), compile-
// time double-buffer offsets via 2x-unrolled tile loop (voff[i]==koff[i]+8192,
// all bases fit 16-bit ds immediates), native bf16 casts for P-packing.
// ---------------------------------------------------------------------------
#define SUBSTEP(BUFB, SS) do { \
    bf16x8 kf0_ = *reinterpret_cast<const bf16x8*>(lds + (BUFB) + koff[(SS)*4 + 0]); \
    bf16x8 kf1_ = *reinterpret_cast<const bf16x8*>(lds + (BUFB) + koff[(SS)*4 + 1]); \
    bf16x8 kf2_ = *reinterpret_cast<const bf16x8*>(lds + (BUFB) + koff[(SS)*4 + 2]); \
    bf16x8 kf3_ = *reinterpret_cast<const bf16x8*>(lds + (BUFB) + koff[(SS)*4 + 3]); \
    f32x16 s_ = {}; \
    __builtin_amdgcn_s_setprio(1); \
    s_ = __builtin_amdgcn_mfma_f32_32x32x16_bf16(kf0_, qf[0], s_, 0, 0, 0); \
    s_ = __builtin_amdgcn_mfma_f32_32x32x16_bf16(kf1_, qf[1], s_, 0, 0, 0); \
    s_ = __builtin_amdgcn_mfma_f32_32x32x16_bf16(kf2_, qf[2], s_, 0, 0, 0); \
    s_ = __builtin_amdgcn_mfma_f32_32x32x16_bf16(kf3_, qf[3], s_, 0, 0, 0); \
    __builtin_amdgcn_s_setprio(0); \
    float m8_[8]; \
    _Pragma("unroll") \
    for (int r = 0; r < 8; ++r) m8_[r] = fmaxf(s_[r], s_[r + 8]); \
    float ml_ = fmaxf(fmaxf(fmaxf(fmaxf(fmaxf(fmaxf(fmaxf( \
        m8_[0], m8_[1]), m8_[2]), m8_[3]), m8_[4]), m8_[5]), m8_[6]), m8_[7]); \
    float mt_ = fmaxf(ml_, __shfl_xor(ml_, 32)); \
    if (!__all(mt_ <= m_run + 8.0f)) { \
        float mn_ = fmaxf(m_run, mt_); \
        float al_ = __builtin_amdgcn_exp2f(m_run - mn_); \
        m_run = mn_; l_run *= al_; accO0 *= al_; accO1 *= al_; \
    } \
    _Pragma("unroll") \
    for (int r = 0; r < 16; ++r) s_[r] = __builtin_amdgcn_exp2f(s_[r] - m_run); \
    float s8_[8]; \
    _Pragma("unroll") \
    for (int r = 0; r < 8; ++r) s8_[r] = s_[r] + s_[r + 8]; \
    float sum_ = ((s8_[0] + s8_[1]) + (s8_[2] + s8_[3])) + ((s8_[4] + s8_[5]) + (s8_[6] + s8_[7])); \
    l_run += sum_ + __shfl_xor(sum_, 32); \
    bf16x8 pa_, pb_; \
    _Pragma("unroll") \
    for (int e = 0; e < 8; ++e) { pa_[e] = (__bf16)s_[e]; pb_[e] = (__bf16)s_[8 + e]; } \
    bf16x8 va0_ = *reinterpret_cast<const bf16x8*>(lds + (BUFB) + 8192 + koff[2 * (SS)]); \
    bf16x8 vb0_ = *reinterpret_cast<const bf16x8*>(lds + (BUFB) + 8192 + koff[2 * (SS) + 1]); \
    bf16x8 va1_ = *reinterpret_cast<const bf16x8*>(lds + (BUFB) + 8192 + koff[4 + 2 * (SS)]); \
    bf16x8 vb1_ = *reinterpret_cast<const bf16x8*>(lds + (BUFB) + 8192 + koff[4 + 2 * (SS) + 1]); \
    __builtin_amdgcn_s_setprio(1); \
    accO0 = __builtin_amdgcn_mfma_f32_32x32x16_bf16(va0_, pa_, accO0, 0, 0, 0); \
    accO0 = __builtin_amdgcn_mfma_f32_32x32x16_bf16(vb0_, pb_, accO0, 0, 0, 0); \
    accO1 = __builtin_amdgcn_mfma_f32_32x32x16_bf16(va1_, pa_, accO1, 0, 0, 0); \
    accO1 = __builtin_amdgcn_mfma_f32_32x32x16_bf16(vb1_, pb_, accO1, 0, 0, 0); \
    __builtin_amdgcn_s_setprio(0); \
} while (0)

#define TILE(BUFB, NBUFB, KT, MORE) do { \
    if (MORE) { \
        const char* gk_ = Kp + (size_t)((KT) + 1) * 8192; \
        gload_lds16(gk_ + kgoff0, lds + (NBUFB) + kdst0); \
        gload_lds16(gk_ + kgoff1, lds + (NBUFB) + kdst1); \
        const char* gv_ = Vp + vgoff + (size_t)((KT) + 1) * 128; \
        v0r = *reinterpret_cast<const bf16x8*>(gv_); \
        v1r = *reinterpret_cast<const bf16x8*>(gv_ + 16); \
    } \
    SUBSTEP(BUFB, 0); \
    SUBSTEP(BUFB, 1); \
    if (MORE) { \
        bf16x8 cA_ = __builtin_shufflevector(v0r, v1r, 0, 1, 2, 3, 8, 9, 10, 11); \
        bf16x8 cB_ = __builtin_shufflevector(v0r, v1r, 4, 5, 6, 7, 12, 13, 14, 15); \
        *reinterpret_cast<bf16x8*>(lds + (NBUFB) + vwoffA)        = cA_; \
        *reinterpret_cast<bf16x8*>(lds + (NBUFB) + (vwoffA ^ 16)) = cB_; \
    } \
    __syncthreads(); \
} while (0)

__global__ __launch_bounds__(256, 4)
void attn(const __bf16* __restrict__ Qb,
          const __bf16* __restrict__ Kb,
          const __bf16* __restrict__ Vt,
          float* __restrict__ out)
{
    __shared__ char lds[32768];   // [buf][K 8KB | V 8KB] x2

    int qt = blockIdx.x;          // 0..15
    int bh = blockIdx.y;          // 0..63
    int b = bh >> 5, h = bh & 31;
    int kvh = h >> 2;             // REP = 4
    int tid = threadIdx.x, wave = tid >> 6, lane = tid & 63;
    int ql = lane & 31, hi = lane >> 5;
    int q0 = qt * 128 + wave * 32;

    const __bf16* Qp = Qb + (size_t)(b * NH + h) * SEQ * HDIM;
    const char*   Kp = (const char*)(Kb + (size_t)(b * NKVH + kvh) * SEQ * HDIM);
    const char*   Vp = (const char*)(Vt + (size_t)(b * NKVH + kvh) * HDIM * SEQ);

    bf16x8 qf[4];
    #pragma unroll
    for (int f = 0; f < 4; ++f)
        qf[f] = *reinterpret_cast<const bf16x8*>(Qp + (size_t)(q0 + ql) * HDIM + f * 16 + hi * 8);

    int Mq = (ql & 7) << 4;
    int kgoff0 = wave * 1024 + ((lane >> 3) << 7) + (((lane & 7) ^ (lane >> 3)) << 4);
    int kgoff1 = kgoff0 + 4096;
    int kdst0 = wave * 1024;
    int kdst1 = kdst0 + 4096;
    int vd = wave * 16 + (lane >> 2);
    int vc = lane & 3;
    size_t vgoff = (size_t)vd * (SEQ * 2) + vc * 32;
    int Mv = (vd & 7) << 4;
    int vwoffA = 8192 + vd * 128 + ((vc * 32) ^ Mv);
    int koff[8];
    #pragma unroll
    for (int kb = 0; kb < 2; ++kb)
        #pragma unroll
        for (int f = 0; f < 4; ++f)
            koff[kb * 4 + f] = (kb * 32 + ql) * 128 + ((f * 32 + hi * 16) ^ Mq);

    f32x16 accO0 = {}, accO1 = {};
    float m_run = -1e30f, l_run = 0.0f;

    bf16x8 v0r, v1r;

    // ---- prologue: stage tile 0 into buf 0 ----
    gload_lds16(Kp + kgoff0, lds + kdst0);
    gload_lds16(Kp + kgoff1, lds + kdst1);
    {
        const char* gv = Vp + vgoff;
        v0r = *reinterpret_cast<const bf16x8*>(gv);
        v1r = *reinterpret_cast<const bf16x8*>(gv + 16);
        bf16x8 cA = __builtin_shufflevector(v0r, v1r, 0, 1, 2, 3, 8, 9, 10, 11);
        bf16x8 cB = __builtin_shufflevector(v0r, v1r, 4, 5, 6, 7, 12, 13, 14, 15);
        *reinterpret_cast<bf16x8*>(lds + vwoffA)        = cA;
        *reinterpret_cast<bf16x8*>(lds + (vwoffA ^ 16)) = cB;
    }
    __syncthreads();

    #pragma unroll 1
    for (int kt2 = 0; kt2 < 15; ++kt2) {
        TILE(0,     16384, 2 * kt2,     true);
        TILE(16384, 0,     2 * kt2 + 1, true);
    }
    TILE(0,     16384, 30, true);
    TILE(16384, 0,     31, false);

    // ---- epilogue ----
    float inv = 1.0f / l_run;
    float* op = out + ((size_t)b * SEQ + q0 + ql) * DMODEL + h * HDIM;
    #pragma unroll
    for (int G = 0; G < 4; ++G) {
        f32x4 o0 = { accO0[4 * G + 0] * inv, accO0[4 * G + 1] * inv,
                     accO0[4 * G + 2] * inv, accO0[4 * G + 3] * inv };
        f32x4 o1 = { accO1[4 * G + 0] * inv, accO1[4 * G + 1] * inv,
                     accO1[4 * G + 2] * inv, accO1[4 * G + 3] * inv };
        *reinterpret_cast<f32x4*>(op + 8 * G + 4 * hi)      = o0;
        *reinterpret_cast<f32x4*>(op + 32 + 8 * G + 4 * hi) = o1;
    }
}

// ---------------------------------------------------------------------------
extern "C" void kernel_launch(void* const* d_in, const int* in_sizes, int n_in,
                              void* d_out, int out_size, void* d_ws, size_t ws_size,
                              hipStream_t stream)
{
    const float* hs = (const float*)d_in[0];
    const float* Wq = (const float*)d_in[1];
    const float* bq = (const float*)d_in[2];
    const float* Wk = (const float*)d_in[3];
    const float* bk = (const float*)d_in[4];
    const float* Wv = (const float*)d_in[5];
    const float* bv = (const float*)d_in[6];
    float* out = (float*)d_out;

    char* ws = (char*)d_ws;
    __bf16* Wt = (__bf16*)(ws);                                   // 12,582,912 B
    __bf16* Ab = (__bf16*)(ws + 12582912);                        // 16,777,216 B
    __bf16* Qb = (__bf16*)(ws + 12582912 + 16777216);             // 16,777,216 B
    __bf16* Kb = (__bf16*)(ws + 12582912 + 2*16777216);           //  4,194,304 B
    __bf16* Vt = (__bf16*)(ws + 12582912 + 2*16777216 + 4194304); //  4,194,304 B

    hipLaunchKernelGGL(cvt_hs,      dim3(4096),   dim3(256), 0, stream, hs, Ab);
    hipLaunchKernelGGL(transpose_w, dim3(32, 48), dim3(256), 0, stream, Wq, Wk, Wv, Wt);
    hipLaunchKernelGGL(qkv_gemm,    dim3(768),    dim3(256), 0, stream, Ab, Wt, bq, bk, bv, Qb, Kb, Vt);
    hipLaunchKernelGGL(attn,        dim3(16, 64), dim3(256), 0, stream, Qb, Kb, Vt, out);
}